// Round 4
// baseline (7141.443 us; speedup 1.0000x reference)
//
#include <hip/hip_runtime.h>
#include <cstdint>
#include <cmath>

#define HW 128
#define NPIX (HW * HW)

typedef _Float16 half8 __attribute__((ext_vector_type(8)));
typedef _Float16 half4 __attribute__((ext_vector_type(4)));
typedef float floatx16 __attribute__((ext_vector_type(16)));

__device__ __forceinline__ float sigf(float x) { return 1.0f / (1.0f + expf(-x)); }

// Device-scope grid barrier for exactly 256 co-resident blocks.
// bar[0] = arrival counter, bar[1] = generation. Zeroed before each launch.
// Release: __threadfence (wbl2+inv) before arrival; last arriver resets cnt
// (ordered by RELEASE gen store). Poll: RELAXED agent atomic load (sc1 ->
// reads coherence point, no per-poll cache inv). Acquire: __threadfence after.
__device__ __forceinline__ void grid_sync(unsigned* bar)
{
    __syncthreads();
    if (threadIdx.x == 0) {
        __threadfence();
        unsigned gen = __hip_atomic_load(bar + 1, __ATOMIC_RELAXED, __HIP_MEMORY_SCOPE_AGENT);
        unsigned a = __hip_atomic_fetch_add(bar, 1u, __ATOMIC_ACQ_REL, __HIP_MEMORY_SCOPE_AGENT);
        if (a == 255u) {
            __hip_atomic_store(bar, 0u, __ATOMIC_RELAXED, __HIP_MEMORY_SCOPE_AGENT);
            __hip_atomic_store(bar + 1, gen + 1u, __ATOMIC_RELEASE, __HIP_MEMORY_SCOPE_AGENT);
        } else {
            while (__hip_atomic_load(bar + 1, __ATOMIC_RELAXED, __HIP_MEMORY_SCOPE_AGENT) == gen)
                __builtin_amdgcn_s_sleep(4);
        }
        __threadfence();
    }
    __syncthreads();
}

// ---------------------------------------------------------------------------
// One ConvLSTM cell phase. Block covers an 8x8 px tile, ALL 256 gate rows.
// 8 waves = 4 hg x 2 px-halves. Wave: 64 gate rows (one hg) x 32 px (4x8).
// B-frag px map: col=lane&31 -> (row 4*ph+(col>>3), col&7). acc0=i/f, acc1=o/g.
// LDS: [100 halo px][NCHP][8 halfs], NCHP=NCH+1 -> conflict-free ds_read_b128.
// ---------------------------------------------------------------------------
template<int NKC, bool CELL1>
__device__ __forceinline__ void cell_phase(
    const _Float16* __restrict__ srcA,   // cell1: xh_t [px][16]; cell2: h0 [px][64]
    const _Float16* __restrict__ srcB,   // h_prev of this cell [px][64]
    const _Float16* __restrict__ Wp,     // packed [NKC][9][8 mf][512]
    const float* bias_lds,               // 256 biases in LDS
    float* __restrict__ c_io,            // [px][64] fp32 in-place
    _Float16* __restrict__ h_out,        // [px][64] fp16
    _Float16* stage, int y0, int x0)
{
    constexpr int NCH = 2 * NKC, NCHP = NCH + 1;
    const int tid = threadIdx.x;

    // ---- stage halo 10x10 px x NCH chunks (zero-padded at borders) ----
    for (int i = tid; i < 100 * NCH; i += 512) {
        int ks, pc;
        if constexpr (NCH == 16) { ks = i & 15; pc = i >> 4; }
        else                     { ks = i % NCH; pc = i / NCH; }
        int r = pc / 10, c = pc - r * 10;
        int gy = y0 - 1 + r, gx = x0 - 1 + c;
        half8 v = {0, 0, 0, 0, 0, 0, 0, 0};
        if (gy >= 0 && gy < HW && gx >= 0 && gx < HW) {
            int px = gy * HW + gx;
            if constexpr (CELL1)
                v = (ks < 2) ? *(const half8*)(srcA + px * 16 + ks * 8)
                             : *(const half8*)(srcB + (size_t)px * 64 + (ks - 2) * 8);
            else
                v = (ks < 8) ? *(const half8*)(srcA + (size_t)px * 64 + ks * 8)
                             : *(const half8*)(srcB + (size_t)px * 64 + (ks - 8) * 8);
        }
        *(half8*)(stage + ((size_t)pc * NCHP + ks) * 8) = v;
    }
    __syncthreads();

    const int lane = tid & 63;
    const int w    = tid >> 6;
    const int hg   = w >> 1;            // 0..3
    const int ph   = w & 1;             // px half: tile rows 4*ph..4*ph+3
    const int l5   = lane >> 5;
    const int col  = lane & 31;
    const int rl   = col >> 3, cl = col & 7;

    floatx16 acc0 = {0,0,0,0,0,0,0,0,0,0,0,0,0,0,0,0};
    floatx16 acc1 = {0,0,0,0,0,0,0,0,0,0,0,0,0,0,0,0};

    const _Float16* wbase = Wp + hg * 1024 + lane * 8;
    #pragma unroll
    for (int kc = 0; kc < NKC; ++kc) {
        half8 a[9][2];
        const _Float16* ap = wbase + (size_t)kc * 9 * 4096;
        #pragma unroll
        for (int tap = 0; tap < 9; ++tap) {
            a[tap][0] = *(const half8*)(ap + tap * 4096);
            a[tap][1] = *(const half8*)(ap + tap * 4096 + 512);
        }
        const int chunk = kc * 2 + l5;
        #pragma unroll
        for (int tap = 0; tap < 9; ++tap) {
            const int dy = tap / 3, dx = tap - dy * 3;
            const int pc = (4 * ph + rl + dy) * 10 + cl + dx;
            half8 b = *(const half8*)(stage + ((size_t)pc * NCHP + chunk) * 8);
            acc0 = __builtin_amdgcn_mfma_f32_32x32x16_f16(a[tap][0], b, acc0, 0, 0, 0);
            acc1 = __builtin_amdgcn_mfma_f32_32x32x16_f16(a[tap][1], b, acc1, 0, 0, 0);
        }
    }

    // ---- LSTM epilogue. C/D: col=lane&31 -> px; row rr=(r&3)+8*(r>>2)+4*l5;
    //      rr<16 -> gates i (acc0) / o (acc1); rr>=16 -> f / g. ----
    const int gy = y0 + 4 * ph + rl;
    const int gx = x0 + cl;
    const size_t pxo = (size_t)(gy * HW + gx) * 64;
    #pragma unroll
    for (int q = 0; q < 2; ++q) {
        int ch0 = hg * 16 + 4 * l5 + 8 * q;
        float bi[4], bf[4], bo[4], bg[4];
        #pragma unroll
        for (int lo = 0; lo < 4; ++lo) {
            bi[lo] = bias_lds[      ch0 + lo];
            bf[lo] = bias_lds[ 64 + ch0 + lo];
            bo[lo] = bias_lds[128 + ch0 + lo];
            bg[lo] = bias_lds[192 + ch0 + lo];
        }
        float4 cp4 = *(const float4*)(c_io + pxo + ch0);
        float cpv[4] = {cp4.x, cp4.y, cp4.z, cp4.w};
        float cn[4];
        half4 hn;
        #pragma unroll
        for (int lo = 0; lo < 4; ++lo) {
            int r0_ = 4 * q + lo;
            int r1_ = 8 + 4 * q + lo;
            float iv = sigf(acc0[r0_] + bi[lo]);
            float fv = sigf(acc0[r1_] + bf[lo]);
            float ov = sigf(acc1[r0_] + bo[lo]);
            float gv = tanhf(acc1[r1_] + bg[lo]);
            float cv = fv * cpv[lo] + iv * gv;
            cn[lo] = cv;
            hn[lo] = (_Float16)(ov * tanhf(cv));
        }
        *(float4*)(c_io + pxo + ch0) = make_float4(cn[0], cn[1], cn[2], cn[3]);
        *(half4*)(h_out + pxo + ch0) = hn;
    }
}

// Readout 64->1 conv for this block's 8x8 tile. 8 threads per px (ch chunks),
// shfl reduce. Reads h1 directly from global (L2/L3 resident).
__device__ __forceinline__ void readout_phase(
    const _Float16* __restrict__ h1, const float* wl, float brv,
    float* __restrict__ yout, int y0, int x0)
{
    const int tid = threadIdx.x;
    const int sub = tid & 7;
    const int p   = tid >> 3;            // 0..63
    const int py  = y0 + (p >> 3), px_ = x0 + (p & 7);
    float s = 0.0f;
    #pragma unroll
    for (int dy = -1; dy <= 1; ++dy) {
        int gy = py + dy;
        if (gy < 0 || gy >= HW) continue;
        #pragma unroll
        for (int dx = -1; dx <= 1; ++dx) {
            int gx = px_ + dx;
            if (gx < 0 || gx >= HW) continue;
            half8 hv = *(const half8*)(h1 + (size_t)(gy * HW + gx) * 64 + sub * 8);
            int tap = (dy + 1) * 3 + (dx + 1);
            #pragma unroll
            for (int j = 0; j < 8; ++j)
                s += wl[(sub * 8 + j) * 9 + tap] * (float)hv[j];
        }
    }
    s += __shfl_xor(s, 1);
    s += __shfl_xor(s, 2);
    s += __shfl_xor(s, 4);
    if (sub == 0) yout[py * HW + px_] = s + brv;
}

__global__ __launch_bounds__(512, 2)
void mega(const _Float16* __restrict__ xh,
          const _Float16* __restrict__ Wp0, const _Float16* __restrict__ Wp1,
          const float* __restrict__ b0g, const float* __restrict__ b1g,
          const float* __restrict__ Wr, const float* __restrict__ br,
          float* __restrict__ c0, float* __restrict__ c1,
          _Float16* __restrict__ h0a, _Float16* __restrict__ h0b,
          _Float16* __restrict__ h1a, _Float16* __restrict__ h1b,
          float* __restrict__ y, unsigned* bar)
{
    __shared__ __align__(16) _Float16 stage[100 * 17 * 8];   // 27.2 KB
    __shared__ float wl[576];
    __shared__ float blds[512];

    const int tid = threadIdx.x;
    for (int i = tid; i < 576; i += 512) wl[i] = Wr[i];
    for (int i = tid; i < 512; i += 512) blds[i] = (i < 256) ? b0g[i] : b1g[i - 256];
    const float brv = br[0];

    // XCD-chunked tile map: 16x16 tiles of 8x8 px; each XCD owns a 4x8 region.
    const int bid = blockIdx.x;
    const int xcd = bid & 7, lid = bid >> 3;
    const int ty = (xcd >> 1) * 4 + (lid >> 3);
    const int tx = (xcd & 1) * 8 + (lid & 7);
    const int y0 = ty * 8, x0 = tx * 8;
    __syncthreads();

    for (int t = 0; t < 32; ++t) {
        const _Float16* xt = xh + (size_t)t * NPIX * 16;
        _Float16* h0r = (t & 1) ? h0b : h0a;
        _Float16* h0w = (t & 1) ? h0a : h0b;
        _Float16* h1r = (t & 1) ? h1b : h1a;
        _Float16* h1w = (t & 1) ? h1a : h1b;

        cell_phase<5, true>(xt, h0r, Wp0, blds, c0, h0w, stage, y0, x0);
        if (t > 0) readout_phase(h1r, wl, brv, y + (size_t)(t - 1) * NPIX, y0, x0);
        grid_sync(bar);

        cell_phase<8, false>(h0w, h1r, Wp1, blds + 256, c1, h1w, stage, y0, x0);
        grid_sync(bar);
    }
    readout_phase(h1a, wl, brv, y + (size_t)31 * NPIX, y0, x0);   // t=31 -> h1a
}

// ---------------------------------------------------------------------------
// Weight repack (unchanged layout): W [256][CIN_W][3][3] fp32 ->
// Wp [NKC][9][8 mf][64 lanes][8] fp16. k = kc*16 + (lane>>5)*8 + j.
// ---------------------------------------------------------------------------
__global__ void pack_w(const float* __restrict__ W, _Float16* __restrict__ Wp,
                       int NKC, int CIN_W, int cell1, int total)
{
    int idx = blockIdx.x * 256 + threadIdx.x;
    if (idx >= total) return;
    int j  = idx & 7;
    int l  = (idx >> 3) & 63;
    int mf = (idx >> 9) & 7;
    int kt = idx >> 12;                 // kc*9 + tap
    int tap = kt % 9, kc = kt / 9;
    int rr = l & 31, l5 = l >> 5;
    int f = mf & 1, hg = mf >> 1;
    int gate = f * 2 + (rr >> 4);
    int hid  = hg * 16 + (rr & 15);
    int o = gate * 64 + hid;
    int k = kc * 16 + l5 * 8 + j;
    int cin;
    if (cell1) cin = (k < 4) ? k : ((k >= 16 && k < 80) ? (k - 12) : -1);
    else       cin = k;
    float v = (cin >= 0) ? W[((size_t)o * CIN_W + cin) * 9 + tap] : 0.0f;
    Wp[idx] = (_Float16)v;
}

// x [32][4][128][128] fp32 -> xh [32][px][16] fp16 (ch 0-3 real, 4-15 zero)
__global__ void xconv(const float* __restrict__ x, _Float16* __restrict__ xh)
{
    int idx = blockIdx.x * 256 + threadIdx.x;       // 524288
    int t = idx >> 14, px = idx & 16383;
    const float* xs = x + (size_t)t * 4 * NPIX + px;
    half8 v = {0, 0, 0, 0, 0, 0, 0, 0};
    v[0] = (_Float16)xs[0];
    v[1] = (_Float16)xs[NPIX];
    v[2] = (_Float16)xs[2 * NPIX];
    v[3] = (_Float16)xs[3 * NPIX];
    half8 z = {0, 0, 0, 0, 0, 0, 0, 0};
    *(half8*)(xh + (size_t)idx * 16)     = v;
    *(half8*)(xh + (size_t)idx * 16 + 8) = z;
}

extern "C" void kernel_launch(void* const* d_in, const int* in_sizes, int n_in,
                              void* d_out, int out_size, void* d_ws, size_t ws_size,
                              hipStream_t stream)
{
    const float* x  = (const float*)d_in[0];
    const float* W0 = (const float*)d_in[1];
    const float* b0 = (const float*)d_in[2];
    const float* W1 = (const float*)d_in[3];
    const float* b1 = (const float*)d_in[4];
    const float* Wr = (const float*)d_in[5];
    const float* br = (const float*)d_in[6];
    float* y = (float*)d_out;

    char* ws = (char*)d_ws;
    float*    c0  = (float*)(ws);                       // 4 MB
    float*    c1  = (float*)(ws + (4u << 20));          // 4 MB
    _Float16* h0a = (_Float16*)(ws + (8u << 20));       // 2 MB
    _Float16* h1a = (_Float16*)(ws + (10u << 20));      // 2 MB
    _Float16* h0b = (_Float16*)(ws + (12u << 20));      // 2 MB
    _Float16* h1b = (_Float16*)(ws + (14u << 20));      // 2 MB
    _Float16* xh  = (_Float16*)(ws + (16u << 20));      // 16 MB
    _Float16* Wp0 = (_Float16*)(ws + (32u << 20));      // 360 KB
    _Float16* Wp1 = (_Float16*)(ws + (33u << 20));      // 576 KB
    unsigned* bar = (unsigned*)(ws + (34u << 20));      // 64 B

    // zero state read at t=0 (c0, c1, h0a, h1a) + barrier counters
    hipMemsetAsync(ws, 0, (12u << 20), stream);
    hipMemsetAsync(bar, 0, 64, stream);

    pack_w<<<dim3((184320 + 255) / 256), 256, 0, stream>>>(W0, Wp0, 5, 68, 1, 184320);
    pack_w<<<dim3((294912 + 255) / 256), 256, 0, stream>>>(W1, Wp1, 8, 128, 0, 294912);
    xconv<<<dim3(2048), 256, 0, stream>>>(x, xh);

    mega<<<dim3(256), 512, 0, stream>>>(xh, Wp0, Wp1, b0, b1, Wr, br,
                                        c0, c1, h0a, h0b, h1a, h1b, y, bar);
}

// Round 5
// 5882.603 us; speedup vs baseline: 1.2140x; 1.2140x over previous
//
#include <hip/hip_runtime.h>
#include <cstdint>
#include <cmath>

#define HW 128
#define NPIX (HW * HW)

typedef _Float16 half8 __attribute__((ext_vector_type(8)));
typedef _Float16 half4 __attribute__((ext_vector_type(4)));
typedef float floatx16 __attribute__((ext_vector_type(16)));
typedef unsigned long long u64;

__device__ __forceinline__ float sigf(float x) { return 1.0f / (1.0f + expf(-x)); }

// --- device-coherent (cross-XCD) accesses: relaxed agent-scope atomics ---
// These compile to sc1-flagged global ops that bypass the per-XCD L2 and hit
// the device coherence point (Infinity Cache). No cache invalidation needed.
__device__ __forceinline__ half8 ld_coh16(const _Float16* p) {
    const u64* q = (const u64*)p;
    union { u64 u[2]; half8 h; } cv;
    cv.u[0] = __hip_atomic_load(q,     __ATOMIC_RELAXED, __HIP_MEMORY_SCOPE_AGENT);
    cv.u[1] = __hip_atomic_load(q + 1, __ATOMIC_RELAXED, __HIP_MEMORY_SCOPE_AGENT);
    return cv.h;
}
__device__ __forceinline__ void st_coh8(_Float16* p, half4 v) {
    union { half4 h; u64 u; } cv; cv.h = v;
    __hip_atomic_store((u64*)p, cv.u, __ATOMIC_RELAXED, __HIP_MEMORY_SCOPE_AGENT);
}

// Monotonic reset-free 2-level grid barrier for 256 co-resident blocks.
// Instance k = 1,2,...  cnt_x[grp] counts 32 arrivals per group; the 32nd
// arrival (a == 32k-1) bumps cnt_g; everyone polls cnt_g >= 8k. All relaxed
// agent atomics -> no fences -> L2 contents (weights!) survive.
// __syncthreads() drains each wave's vmcnt first, so all sc1 h-stores are
// globally visible before this block's arrival is published.
__device__ __forceinline__ void grid_sync(unsigned* cnt_x, unsigned* cnt_g,
                                          int grp, unsigned k)
{
    __syncthreads();
    if (threadIdx.x == 0) {
        unsigned a = __hip_atomic_fetch_add(cnt_x + grp, 1u,
                         __ATOMIC_RELAXED, __HIP_MEMORY_SCOPE_AGENT);
        if (a == 32u * k - 1u)
            __hip_atomic_fetch_add(cnt_g, 1u,
                __ATOMIC_RELAXED, __HIP_MEMORY_SCOPE_AGENT);
        while (__hip_atomic_load(cnt_g, __ATOMIC_RELAXED,
                                 __HIP_MEMORY_SCOPE_AGENT) < 8u * k)
            __builtin_amdgcn_s_sleep(2);
    }
    __syncthreads();
}

// ---------------------------------------------------------------------------
// One ConvLSTM cell phase. Block covers an 8x8 px tile, ALL 256 gate rows.
// 8 waves = 4 hg x 2 px-halves. Wave: 64 gate rows (one hg) x 32 px (4x8).
// h buffers are accessed coherently (sc1); xh/weights/bias/c via cached path.
// ---------------------------------------------------------------------------
template<int NKC, bool CELL1>
__device__ __forceinline__ void cell_phase(
    const _Float16* __restrict__ srcA,   // cell1: xh_t [px][16] (cached); cell2: h0 [px][64] (coh)
    const _Float16* __restrict__ srcB,   // h_prev of this cell [px][64] (coh)
    const _Float16* __restrict__ Wp,     // packed [NKC][9][8 mf][512] (cached, L2-resident)
    const float* bias_lds,               // 256 biases in LDS
    float* __restrict__ c_io,            // [px][64] fp32, block-private, cached
    _Float16* __restrict__ h_out,        // [px][64] fp16, coherent stores
    _Float16* stage, int y0, int x0)
{
    constexpr int NCH = 2 * NKC, NCHP = NCH + 1;
    const int tid = threadIdx.x;

    // ---- stage halo 10x10 px x NCH chunks (zero-padded at borders) ----
    for (int i = tid; i < 100 * NCH; i += 512) {
        int ks, pc;
        if constexpr (NCH == 16) { ks = i & 15; pc = i >> 4; }
        else                     { ks = i % NCH; pc = i / NCH; }
        int r = pc / 10, c = pc - r * 10;
        int gy = y0 - 1 + r, gx = x0 - 1 + c;
        half8 v = {0, 0, 0, 0, 0, 0, 0, 0};
        if (gy >= 0 && gy < HW && gx >= 0 && gx < HW) {
            int px = gy * HW + gx;
            if constexpr (CELL1)
                v = (ks < 2) ? *(const half8*)(srcA + px * 16 + ks * 8)
                             : ld_coh16(srcB + (size_t)px * 64 + (ks - 2) * 8);
            else
                v = (ks < 8) ? ld_coh16(srcA + (size_t)px * 64 + ks * 8)
                             : ld_coh16(srcB + (size_t)px * 64 + (ks - 8) * 8);
        }
        *(half8*)(stage + ((size_t)pc * NCHP + ks) * 8) = v;
    }
    __syncthreads();

    const int lane = tid & 63;
    const int w    = tid >> 6;
    const int hg   = w >> 1;            // 0..3
    const int ph   = w & 1;             // px half: tile rows 4*ph..4*ph+3
    const int l5   = lane >> 5;
    const int col  = lane & 31;
    const int rl   = col >> 3, cl = col & 7;

    floatx16 acc0 = {0,0,0,0,0,0,0,0,0,0,0,0,0,0,0,0};
    floatx16 acc1 = {0,0,0,0,0,0,0,0,0,0,0,0,0,0,0,0};

    const _Float16* wbase = Wp + hg * 1024 + lane * 8;
    #pragma unroll
    for (int kc = 0; kc < NKC; ++kc) {
        half8 a[9][2];
        const _Float16* ap = wbase + (size_t)kc * 9 * 4096;
        #pragma unroll
        for (int tap = 0; tap < 9; ++tap) {
            a[tap][0] = *(const half8*)(ap + tap * 4096);
            a[tap][1] = *(const half8*)(ap + tap * 4096 + 512);
        }
        const int chunk = kc * 2 + l5;
        #pragma unroll
        for (int tap = 0; tap < 9; ++tap) {
            const int dy = tap / 3, dx = tap - dy * 3;
            const int pc = (4 * ph + rl + dy) * 10 + cl + dx;
            half8 b = *(const half8*)(stage + ((size_t)pc * NCHP + chunk) * 8);
            acc0 = __builtin_amdgcn_mfma_f32_32x32x16_f16(a[tap][0], b, acc0, 0, 0, 0);
            acc1 = __builtin_amdgcn_mfma_f32_32x32x16_f16(a[tap][1], b, acc1, 0, 0, 0);
        }
    }

    // ---- LSTM epilogue. C/D: col=lane&31 -> px; row rr=(r&3)+8*(r>>2)+4*l5;
    //      rr<16 -> gates i (acc0) / o (acc1); rr>=16 -> f / g. ----
    const int gy = y0 + 4 * ph + rl;
    const int gx = x0 + cl;
    const size_t pxo = (size_t)(gy * HW + gx) * 64;
    #pragma unroll
    for (int q = 0; q < 2; ++q) {
        int ch0 = hg * 16 + 4 * l5 + 8 * q;
        float bi[4], bf[4], bo[4], bg[4];
        #pragma unroll
        for (int lo = 0; lo < 4; ++lo) {
            bi[lo] = bias_lds[      ch0 + lo];
            bf[lo] = bias_lds[ 64 + ch0 + lo];
            bo[lo] = bias_lds[128 + ch0 + lo];
            bg[lo] = bias_lds[192 + ch0 + lo];
        }
        float4 cp4 = *(const float4*)(c_io + pxo + ch0);
        float cpv[4] = {cp4.x, cp4.y, cp4.z, cp4.w};
        float cn[4];
        half4 hn;
        #pragma unroll
        for (int lo = 0; lo < 4; ++lo) {
            int r0_ = 4 * q + lo;
            int r1_ = 8 + 4 * q + lo;
            float iv = sigf(acc0[r0_] + bi[lo]);
            float fv = sigf(acc0[r1_] + bf[lo]);
            float ov = sigf(acc1[r0_] + bo[lo]);
            float gv = tanhf(acc1[r1_] + bg[lo]);
            float cv = fv * cpv[lo] + iv * gv;
            cn[lo] = cv;
            hn[lo] = (_Float16)(ov * tanhf(cv));
        }
        *(float4*)(c_io + pxo + ch0) = make_float4(cn[0], cn[1], cn[2], cn[3]);
        st_coh8(h_out + pxo + ch0, hn);
    }
}

// Readout 64->1 conv for this block's 8x8 tile. 8 threads per px (ch chunks),
// shfl reduce. h1 read coherently (written by neighbor blocks last phase).
__device__ __forceinline__ void readout_phase(
    const _Float16* __restrict__ h1, const float* wl, float brv,
    float* __restrict__ yout, int y0, int x0)
{
    const int tid = threadIdx.x;
    const int sub = tid & 7;
    const int p   = tid >> 3;            // 0..63
    const int py  = y0 + (p >> 3), px_ = x0 + (p & 7);
    float s = 0.0f;
    #pragma unroll
    for (int dy = -1; dy <= 1; ++dy) {
        int gy = py + dy;
        if (gy < 0 || gy >= HW) continue;
        #pragma unroll
        for (int dx = -1; dx <= 1; ++dx) {
            int gx = px_ + dx;
            if (gx < 0 || gx >= HW) continue;
            half8 hv = ld_coh16(h1 + (size_t)(gy * HW + gx) * 64 + sub * 8);
            int tap = (dy + 1) * 3 + (dx + 1);
            #pragma unroll
            for (int j = 0; j < 8; ++j)
                s += wl[(sub * 8 + j) * 9 + tap] * (float)hv[j];
        }
    }
    s += __shfl_xor(s, 1);
    s += __shfl_xor(s, 2);
    s += __shfl_xor(s, 4);
    if (sub == 0) yout[py * HW + px_] = s + brv;
}

__global__ __launch_bounds__(512, 2)
void mega(const _Float16* __restrict__ xh,
          const _Float16* __restrict__ Wp0, const _Float16* __restrict__ Wp1,
          const float* __restrict__ b0g, const float* __restrict__ b1g,
          const float* __restrict__ Wr, const float* __restrict__ br,
          float* __restrict__ c0, float* __restrict__ c1,
          _Float16* __restrict__ h0a, _Float16* __restrict__ h0b,
          _Float16* __restrict__ h1a, _Float16* __restrict__ h1b,
          float* __restrict__ y, unsigned* cnt_x, unsigned* cnt_g)
{
    __shared__ __align__(16) _Float16 stage[100 * 17 * 8];   // 27.2 KB
    __shared__ float wl[576];
    __shared__ float blds[512];

    const int tid = threadIdx.x;
    for (int i = tid; i < 576; i += 512) wl[i] = Wr[i];
    for (int i = tid; i < 512; i += 512) blds[i] = (i < 256) ? b0g[i] : b1g[i - 256];
    const float brv = br[0];

    // XCD-chunked tile map: 16x16 tiles of 8x8 px; each XCD owns a 4x8 region.
    const int bid = blockIdx.x;
    const int grp = bid & 7, lid = bid >> 3;
    const int ty = (grp >> 1) * 4 + (lid >> 3);
    const int tx = (grp & 1) * 8 + (lid & 7);
    const int y0 = ty * 8, x0 = tx * 8;
    __syncthreads();

    for (int t = 0; t < 32; ++t) {
        const _Float16* xt = xh + (size_t)t * NPIX * 16;
        _Float16* h0r = (t & 1) ? h0b : h0a;
        _Float16* h0w = (t & 1) ? h0a : h0b;
        _Float16* h1r = (t & 1) ? h1b : h1a;
        _Float16* h1w = (t & 1) ? h1a : h1b;

        cell_phase<5, true>(xt, h0r, Wp0, blds, c0, h0w, stage, y0, x0);
        if (t > 0) readout_phase(h1r, wl, brv, y + (size_t)(t - 1) * NPIX, y0, x0);
        grid_sync(cnt_x, cnt_g, grp, 2u * t + 1u);

        cell_phase<8, false>(h0w, h1r, Wp1, blds + 256, c1, h1w, stage, y0, x0);
        grid_sync(cnt_x, cnt_g, grp, 2u * t + 2u);
    }
    readout_phase(h1a, wl, brv, y + (size_t)31 * NPIX, y0, x0);   // t=31 -> h1a
}

// ---------------------------------------------------------------------------
// Weight repack (unchanged layout): W [256][CIN_W][3][3] fp32 ->
// Wp [NKC][9][8 mf][64 lanes][8] fp16. k = kc*16 + (lane>>5)*8 + j.
// ---------------------------------------------------------------------------
__global__ void pack_w(const float* __restrict__ W, _Float16* __restrict__ Wp,
                       int NKC, int CIN_W, int cell1, int total)
{
    int idx = blockIdx.x * 256 + threadIdx.x;
    if (idx >= total) return;
    int j  = idx & 7;
    int l  = (idx >> 3) & 63;
    int mf = (idx >> 9) & 7;
    int kt = idx >> 12;                 // kc*9 + tap
    int tap = kt % 9, kc = kt / 9;
    int rr = l & 31, l5 = l >> 5;
    int f = mf & 1, hg = mf >> 1;
    int gate = f * 2 + (rr >> 4);
    int hid  = hg * 16 + (rr & 15);
    int o = gate * 64 + hid;
    int k = kc * 16 + l5 * 8 + j;
    int cin;
    if (cell1) cin = (k < 4) ? k : ((k >= 16 && k < 80) ? (k - 12) : -1);
    else       cin = k;
    float v = (cin >= 0) ? W[((size_t)o * CIN_W + cin) * 9 + tap] : 0.0f;
    Wp[idx] = (_Float16)v;
}

// x [32][4][128][128] fp32 -> xh [32][px][16] fp16 (ch 0-3 real, 4-15 zero)
__global__ void xconv(const float* __restrict__ x, _Float16* __restrict__ xh)
{
    int idx = blockIdx.x * 256 + threadIdx.x;       // 524288
    int t = idx >> 14, px = idx & 16383;
    const float* xs = x + (size_t)t * 4 * NPIX + px;
    half8 v = {0, 0, 0, 0, 0, 0, 0, 0};
    v[0] = (_Float16)xs[0];
    v[1] = (_Float16)xs[NPIX];
    v[2] = (_Float16)xs[2 * NPIX];
    v[3] = (_Float16)xs[3 * NPIX];
    half8 z = {0, 0, 0, 0, 0, 0, 0, 0};
    *(half8*)(xh + (size_t)idx * 16)     = v;
    *(half8*)(xh + (size_t)idx * 16 + 8) = z;
}

extern "C" void kernel_launch(void* const* d_in, const int* in_sizes, int n_in,
                              void* d_out, int out_size, void* d_ws, size_t ws_size,
                              hipStream_t stream)
{
    const float* x  = (const float*)d_in[0];
    const float* W0 = (const float*)d_in[1];
    const float* b0 = (const float*)d_in[2];
    const float* W1 = (const float*)d_in[3];
    const float* b1 = (const float*)d_in[4];
    const float* Wr = (const float*)d_in[5];
    const float* br = (const float*)d_in[6];
    float* y = (float*)d_out;

    char* ws = (char*)d_ws;
    float*    c0  = (float*)(ws);                       // 4 MB
    float*    c1  = (float*)(ws + (4u << 20));          // 4 MB
    _Float16* h0a = (_Float16*)(ws + (8u << 20));       // 2 MB
    _Float16* h1a = (_Float16*)(ws + (10u << 20));      // 2 MB
    _Float16* h0b = (_Float16*)(ws + (12u << 20));      // 2 MB
    _Float16* h1b = (_Float16*)(ws + (14u << 20));      // 2 MB
    _Float16* xh  = (_Float16*)(ws + (16u << 20));      // 16 MB
    _Float16* Wp0 = (_Float16*)(ws + (32u << 20));      // 360 KB
    _Float16* Wp1 = (_Float16*)(ws + (33u << 20));      // 576 KB
    unsigned* cnt = (unsigned*)(ws + (34u << 20));      // 64 B: [0..7]=cnt_x, [8]=cnt_g

    // zero state read at t=0 (c0, c1, h0a, h1a) + barrier counters
    hipMemsetAsync(ws, 0, (12u << 20), stream);
    hipMemsetAsync(cnt, 0, 64, stream);

    pack_w<<<dim3((184320 + 255) / 256), 256, 0, stream>>>(W0, Wp0, 5, 68, 1, 184320);
    pack_w<<<dim3((294912 + 255) / 256), 256, 0, stream>>>(W1, Wp1, 8, 128, 0, 294912);
    xconv<<<dim3(2048), 256, 0, stream>>>(x, xh);

    mega<<<dim3(256), 512, 0, stream>>>(xh, Wp0, Wp1, b0, b1, Wr, br,
                                        c0, c1, h0a, h0b, h1a, h1b, y,
                                        cnt, cnt + 8);
}

// Round 6
// 4413.774 us; speedup vs baseline: 1.6180x; 1.3328x over previous
//
#include <hip/hip_runtime.h>
#include <cstdint>
#include <cmath>

#define HW 128
#define NPIX (HW * HW)

typedef _Float16 half8 __attribute__((ext_vector_type(8)));
typedef _Float16 half4 __attribute__((ext_vector_type(4)));
typedef float floatx16 __attribute__((ext_vector_type(16)));

__device__ __forceinline__ float sigf(float x) { return 1.0f / (1.0f + expf(-x)); }

// --- coalesced device-coherent accesses (bypass L1+L2, hit IF): sc0 sc1 ---
__device__ __forceinline__ half8 ld_coh16(const _Float16* p) {
    half8 v;
    asm volatile("global_load_dwordx4 %0, %1, off sc0 sc1\n\ts_waitcnt vmcnt(0)"
                 : "=&v"(v) : "v"(p) : "memory");
    return v;
}
__device__ __forceinline__ void st_coh8(_Float16* p, half4 v) {
    asm volatile("global_store_dwordx2 %0, %1, off sc0 sc1"
                 :: "v"(p), "v"(v) : "memory");
}

// Monotonic reset-free 2-level grid barrier for 256 co-resident blocks.
// All relaxed agent atomics -> no fences -> L2 contents (weights, c, h_priv)
// survive. Explicit vmcnt drain makes this wave's coherent stores globally
// visible before arrival is published.
__device__ __forceinline__ void grid_sync(unsigned* cnt_x, unsigned* cnt_g,
                                          int grp, unsigned k)
{
    asm volatile("s_waitcnt vmcnt(0)" ::: "memory");
    __syncthreads();
    if (threadIdx.x == 0) {
        unsigned a = __hip_atomic_fetch_add(cnt_x + grp, 1u,
                         __ATOMIC_RELAXED, __HIP_MEMORY_SCOPE_AGENT);
        if (a == 32u * k - 1u)
            __hip_atomic_fetch_add(cnt_g, 1u,
                __ATOMIC_RELAXED, __HIP_MEMORY_SCOPE_AGENT);
        while (__hip_atomic_load(cnt_g, __ATOMIC_RELAXED,
                                 __HIP_MEMORY_SCOPE_AGENT) < 8u * k)
            __builtin_amdgcn_s_sleep(2);
    }
    __syncthreads();
}

// ---------------------------------------------------------------------------
// One ConvLSTM cell phase. Block = 8x8 px tile, all 256 gate rows.
// 8 waves = 4 hg x 2 px-halves; wave = 64 gate rows x 32 px; 2 MFMA/iter.
// h interior: block-private cached global (h_priv). h ring: coherent buffers.
// ---------------------------------------------------------------------------
template<int NKC, bool CELL1>
__device__ __forceinline__ void cell_phase(
    const _Float16* __restrict__ xt,      // cell1 only: xh [px][8] (cached)
    const _Float16* __restrict__ hA_priv, // h0 interior (priv, cached)
    const _Float16* __restrict__ hA_sh,   // h0 ring (coherent)
    const _Float16* __restrict__ hB_priv, // cell2: h1 interior
    const _Float16* __restrict__ hB_sh,   // cell2: h1 ring
    const _Float16* __restrict__ Wp,      // packed [NKC][9][8 mf][512] (L2)
    const float* bias_lds,                // 256 biases in LDS
    float* __restrict__ c_io,             // [px][64] fp32, block-owned, cached
    _Float16* __restrict__ hO_priv,       // h out interior (priv)
    _Float16* __restrict__ hO_sh,         // h out ring (coherent)
    _Float16* stage, int y0, int x0, int tb)
{
    constexpr int NCH = 2 * NKC, NCHP = NCH + 1;
    const int tid = threadIdx.x;

    // ---- stage halo 10x10 px x NCH chunks ----
    for (int i = tid; i < 100 * NCH; i += 512) {
        int ks, pc;
        if constexpr (NCH == 16) { ks = i & 15; pc = i >> 4; }
        else                     { ks = i % NCH; pc = i / NCH; }
        int r = pc / 10, c = pc - r * 10;
        int gy = y0 - 1 + r, gx = x0 - 1 + c;
        half8 v = {0, 0, 0, 0, 0, 0, 0, 0};
        if (gy >= 0 && gy < HW && gx >= 0 && gx < HW) {
            int px = gy * HW + gx;
            bool inter = (unsigned)(r - 1) < 8u && (unsigned)(c - 1) < 8u;
            int pidx = tb + (r - 1) * 8 + (c - 1);
            if constexpr (CELL1) {
                if (ks == 0)      v = *(const half8*)(xt + (size_t)px * 8);
                else if (ks >= 2) {
                    if (inter) v = *(const half8*)(hA_priv + (size_t)pidx * 64 + (ks - 2) * 8);
                    else       v = ld_coh16(hA_sh + (size_t)px * 64 + (ks - 2) * 8);
                }
                // ks==1: zero (weights for k 8..15 are zero)
            } else {
                const _Float16* priv = (ks < 8) ? hA_priv : hB_priv;
                const _Float16* sh   = (ks < 8) ? hA_sh   : hB_sh;
                int ch = (ks & 7) * 8;
                if (inter) v = *(const half8*)(priv + (size_t)pidx * 64 + ch);
                else       v = ld_coh16(sh + (size_t)px * 64 + ch);
            }
        }
        *(half8*)(stage + ((size_t)pc * NCHP + ks) * 8) = v;
    }
    __syncthreads();

    const int lane = tid & 63;
    const int w    = tid >> 6;
    const int hg   = w >> 1;
    const int ph   = w & 1;
    const int l5   = lane >> 5;
    const int col  = lane & 31;
    const int rl   = col >> 3, cl = col & 7;

    floatx16 acc0 = {0,0,0,0,0,0,0,0,0,0,0,0,0,0,0,0};
    floatx16 acc1 = {0,0,0,0,0,0,0,0,0,0,0,0,0,0,0,0};

    const _Float16* wbase = Wp + hg * 1024 + lane * 8;
    #pragma unroll
    for (int kc = 0; kc < NKC; ++kc) {
        half8 a[9][2];
        const _Float16* ap = wbase + (size_t)kc * 9 * 4096;
        #pragma unroll
        for (int tap = 0; tap < 9; ++tap) {
            a[tap][0] = *(const half8*)(ap + tap * 4096);
            a[tap][1] = *(const half8*)(ap + tap * 4096 + 512);
        }
        const int chunk = kc * 2 + l5;
        #pragma unroll
        for (int tap = 0; tap < 9; ++tap) {
            const int dy = tap / 3, dx = tap - dy * 3;
            const int pc = (4 * ph + rl + dy) * 10 + cl + dx;
            half8 b = *(const half8*)(stage + ((size_t)pc * NCHP + chunk) * 8);
            acc0 = __builtin_amdgcn_mfma_f32_32x32x16_f16(a[tap][0], b, acc0, 0, 0, 0);
            acc1 = __builtin_amdgcn_mfma_f32_32x32x16_f16(a[tap][1], b, acc1, 0, 0, 0);
        }
    }

    // ---- LSTM epilogue. rr=(r&3)+8*(r>>2)+4*l5; rr<16 -> i/o, rr>=16 -> f/g.
    const int lr = 4 * ph + rl, lc = cl;
    const int gy = y0 + lr, gx = x0 + lc;
    const bool bdry = (lr == 0) | (lr == 7) | (lc == 0) | (lc == 7);
    const size_t pxo = (size_t)(gy * HW + gx) * 64;
    const size_t ppo = (size_t)(tb + lr * 8 + lc) * 64;
    #pragma unroll
    for (int q = 0; q < 2; ++q) {
        int ch0 = hg * 16 + 4 * l5 + 8 * q;
        float bi[4], bf[4], bo[4], bg[4];
        #pragma unroll
        for (int lo = 0; lo < 4; ++lo) {
            bi[lo] = bias_lds[      ch0 + lo];
            bf[lo] = bias_lds[ 64 + ch0 + lo];
            bo[lo] = bias_lds[128 + ch0 + lo];
            bg[lo] = bias_lds[192 + ch0 + lo];
        }
        float4 cp4 = *(const float4*)(c_io + pxo + ch0);
        float cpv[4] = {cp4.x, cp4.y, cp4.z, cp4.w};
        float cn[4];
        half4 hn;
        #pragma unroll
        for (int lo = 0; lo < 4; ++lo) {
            int r0_ = 4 * q + lo;
            int r1_ = 8 + 4 * q + lo;
            float iv = sigf(acc0[r0_] + bi[lo]);
            float fv = sigf(acc0[r1_] + bf[lo]);
            float ov = sigf(acc1[r0_] + bo[lo]);
            float gv = tanhf(acc1[r1_] + bg[lo]);
            float cv = fv * cpv[lo] + iv * gv;
            cn[lo] = cv;
            hn[lo] = (_Float16)(ov * tanhf(cv));
        }
        *(float4*)(c_io + pxo + ch0) = make_float4(cn[0], cn[1], cn[2], cn[3]);
        *(half4*)(hO_priv + ppo + ch0) = hn;
        if (bdry) st_coh8(hO_sh + pxo + ch0, hn);
    }
}

// Readout 64->1 conv for this block's 8x8 tile. Stage h1 (priv interior +
// coherent ring) into LDS once, then 8 threads/px + shfl reduce.
__device__ __forceinline__ void readout_phase(
    const _Float16* __restrict__ h1_priv, const _Float16* __restrict__ h1_sh,
    const float* wl, float brv, float* __restrict__ yout,
    int y0, int x0, int tb, _Float16* rlds)
{
    const int tid = threadIdx.x;
    __syncthreads();                       // stage buffer reuse safety
    for (int i = tid; i < 800; i += 512) {
        int ks = i & 7, pc = i >> 3;
        int r = pc / 10, c = pc - r * 10;
        int gy = y0 - 1 + r, gx = x0 - 1 + c;
        half8 v = {0, 0, 0, 0, 0, 0, 0, 0};
        if (gy >= 0 && gy < HW && gx >= 0 && gx < HW) {
            bool inter = (unsigned)(r - 1) < 8u && (unsigned)(c - 1) < 8u;
            if (inter) v = *(const half8*)(h1_priv + (size_t)(tb + (r - 1) * 8 + (c - 1)) * 64 + ks * 8);
            else       v = ld_coh16(h1_sh + (size_t)(gy * HW + gx) * 64 + ks * 8);
        }
        *(half8*)(rlds + (size_t)i * 8) = v;
    }
    __syncthreads();

    const int sub = tid & 7;
    const int p   = tid >> 3;
    const int pr  = p >> 3, pcc = p & 7;
    float s = 0.0f;
    #pragma unroll
    for (int dy = 0; dy < 3; ++dy)
        #pragma unroll
        for (int dx = 0; dx < 3; ++dx) {
            int pc = (pr + dy) * 10 + (pcc + dx);
            half8 hv = *(const half8*)(rlds + ((size_t)pc * 8 + sub) * 8);
            int tap = dy * 3 + dx;
            #pragma unroll
            for (int j = 0; j < 8; ++j)
                s += wl[(sub * 8 + j) * 9 + tap] * (float)hv[j];
        }
    s += __shfl_xor(s, 1);
    s += __shfl_xor(s, 2);
    s += __shfl_xor(s, 4);
    if (sub == 0) yout[(y0 + pr) * HW + (x0 + pcc)] = s + brv;
}

__global__ __launch_bounds__(512, 2)
void mega(const _Float16* __restrict__ xh,
          const _Float16* __restrict__ Wp0, const _Float16* __restrict__ Wp1,
          const float* __restrict__ b0g, const float* __restrict__ b1g,
          const float* __restrict__ Wr, const float* __restrict__ br,
          float* __restrict__ c0, float* __restrict__ c1,
          _Float16* __restrict__ h0a, _Float16* __restrict__ h0b,
          _Float16* __restrict__ h1a, _Float16* __restrict__ h1b,
          _Float16* __restrict__ h0p, _Float16* __restrict__ h1p,
          float* __restrict__ y, unsigned* cnt_x, unsigned* cnt_g)
{
    __shared__ __align__(16) _Float16 stage[100 * 17 * 8];   // 27.2 KB
    __shared__ float wl[576];
    __shared__ float blds[512];

    const int tid = threadIdx.x;
    for (int i = tid; i < 576; i += 512) wl[i] = Wr[i];
    for (int i = tid; i < 512; i += 512) blds[i] = (i < 256) ? b0g[i] : b1g[i - 256];
    const float brv = br[0];

    // XCD-chunked tile map: 16x16 tiles of 8x8 px; each XCD owns a 4x8 region.
    const int bid = blockIdx.x;
    const int grp = bid & 7, lid = bid >> 3;
    const int ty = (grp >> 1) * 4 + (lid >> 3);
    const int tx = (grp & 1) * 8 + (lid & 7);
    const int y0 = ty * 8, x0 = tx * 8;
    const int tb = bid * 64;            // private tile base (px units)
    __syncthreads();

    for (int t = 0; t < 32; ++t) {
        const _Float16* xt = xh + (size_t)t * NPIX * 8;
        _Float16* h0r = (t & 1) ? h0b : h0a;
        _Float16* h0w = (t & 1) ? h0a : h0b;
        _Float16* h1r = (t & 1) ? h1b : h1a;
        _Float16* h1w = (t & 1) ? h1a : h1b;

        cell_phase<5, true>(xt, h0p, h0r, nullptr, nullptr, Wp0, blds,
                            c0, h0p, h0w, stage, y0, x0, tb);
        if (t > 0) readout_phase(h1p, h1r, wl, brv,
                                 y + (size_t)(t - 1) * NPIX, y0, x0, tb, stage);
        grid_sync(cnt_x, cnt_g, grp, 2u * t + 1u);

        cell_phase<8, false>(nullptr, h0p, h0w, h1p, h1r, Wp1, blds + 256,
                             c1, h1p, h1w, stage, y0, x0, tb);
        grid_sync(cnt_x, cnt_g, grp, 2u * t + 2u);
    }
    readout_phase(h1p, h1a, wl, brv, y + (size_t)31 * NPIX, y0, x0, tb, stage);
}

// ---------------------------------------------------------------------------
// Weight repack (unchanged layout): W [256][CIN_W][3][3] fp32 ->
// Wp [NKC][9][8 mf][64 lanes][8] fp16. k = kc*16 + (lane>>5)*8 + j.
// ---------------------------------------------------------------------------
__global__ void pack_w(const float* __restrict__ W, _Float16* __restrict__ Wp,
                       int NKC, int CIN_W, int cell1, int total)
{
    int idx = blockIdx.x * 256 + threadIdx.x;
    if (idx >= total) return;
    int j  = idx & 7;
    int l  = (idx >> 3) & 63;
    int mf = (idx >> 9) & 7;
    int kt = idx >> 12;                 // kc*9 + tap
    int tap = kt % 9, kc = kt / 9;
    int rr = l & 31, l5 = l >> 5;
    int f = mf & 1, hg = mf >> 1;
    int gate = f * 2 + (rr >> 4);
    int hid  = hg * 16 + (rr & 15);
    int o = gate * 64 + hid;
    int k = kc * 16 + l5 * 8 + j;
    int cin;
    if (cell1) cin = (k < 4) ? k : ((k >= 16 && k < 80) ? (k - 12) : -1);
    else       cin = k;
    float v = (cin >= 0) ? W[((size_t)o * CIN_W + cin) * 9 + tap] : 0.0f;
    Wp[idx] = (_Float16)v;
}

// x [32][4][128][128] fp32 -> xh [32][px][8] fp16 (ch 0-3 real, 4-7 zero)
__global__ void xconv(const float* __restrict__ x, _Float16* __restrict__ xh)
{
    int idx = blockIdx.x * 256 + threadIdx.x;       // 524288
    int t = idx >> 14, px = idx & 16383;
    const float* xs = x + (size_t)t * 4 * NPIX + px;
    half8 v = {0, 0, 0, 0, 0, 0, 0, 0};
    v[0] = (_Float16)xs[0];
    v[1] = (_Float16)xs[NPIX];
    v[2] = (_Float16)xs[2 * NPIX];
    v[3] = (_Float16)xs[3 * NPIX];
    *(half8*)(xh + (size_t)idx * 8) = v;
}

extern "C" void kernel_launch(void* const* d_in, const int* in_sizes, int n_in,
                              void* d_out, int out_size, void* d_ws, size_t ws_size,
                              hipStream_t stream)
{
    const float* x  = (const float*)d_in[0];
    const float* W0 = (const float*)d_in[1];
    const float* b0 = (const float*)d_in[2];
    const float* W1 = (const float*)d_in[3];
    const float* b1 = (const float*)d_in[4];
    const float* Wr = (const float*)d_in[5];
    const float* br = (const float*)d_in[6];
    float* y = (float*)d_out;

    char* ws = (char*)d_ws;
    float*    c0  = (float*)(ws);                       // 4 MB
    float*    c1  = (float*)(ws + (4u << 20));          // 4 MB
    _Float16* h0a = (_Float16*)(ws + (8u << 20));       // 2 MB (ring, coh)
    _Float16* h1a = (_Float16*)(ws + (10u << 20));      // 2 MB
    _Float16* h0p = (_Float16*)(ws + (12u << 20));      // 2 MB (private tiles)
    _Float16* h1p = (_Float16*)(ws + (14u << 20));      // 2 MB
    _Float16* h0b = (_Float16*)(ws + (16u << 20));      // 2 MB
    _Float16* h1b = (_Float16*)(ws + (18u << 20));      // 2 MB
    _Float16* xh  = (_Float16*)(ws + (20u << 20));      // 8 MB
    _Float16* Wp0 = (_Float16*)(ws + (28u << 20));      // 360 KB
    _Float16* Wp1 = (_Float16*)(ws + (29u << 20));      // 576 KB
    unsigned* cnt = (unsigned*)(ws + (30u << 20));      // 64 B

    // zero c0,c1, t=0-read ring buffers (h0a,h1a), private h + counters
    hipMemsetAsync(ws, 0, (16u << 20), stream);
    hipMemsetAsync(cnt, 0, 64, stream);

    pack_w<<<dim3((184320 + 255) / 256), 256, 0, stream>>>(W0, Wp0, 5, 68, 1, 184320);
    pack_w<<<dim3((294912 + 255) / 256), 256, 0, stream>>>(W1, Wp1, 8, 128, 0, 294912);
    xconv<<<dim3(2048), 256, 0, stream>>>(x, xh);

    mega<<<dim3(256), 512, 0, stream>>>(xh, Wp0, Wp1, b0, b1, Wr, br,
                                        c0, c1, h0a, h0b, h1a, h1b,
                                        h0p, h1p, y, cnt, cnt + 8);
}

// Round 7
// 4225.714 us; speedup vs baseline: 1.6900x; 1.0445x over previous
//
#include <hip/hip_runtime.h>
#include <cstdint>
#include <cmath>

#define HW 128
#define NPIX (HW * HW)

typedef _Float16 half8 __attribute__((ext_vector_type(8)));
typedef _Float16 half4 __attribute__((ext_vector_type(4)));
typedef float floatx16 __attribute__((ext_vector_type(16)));

__device__ __forceinline__ float sigf(float x) { return 1.0f / (1.0f + expf(-x)); }

// --- coalesced device-coherent accesses (bypass L1+L2, hit IF): sc0 sc1 ---
__device__ __forceinline__ half8 ld_coh16(const _Float16* p) {
    half8 v;
    asm volatile("global_load_dwordx4 %0, %1, off sc0 sc1\n\ts_waitcnt vmcnt(0)"
                 : "=&v"(v) : "v"(p) : "memory");
    return v;
}
__device__ __forceinline__ void st_coh8(_Float16* p, half4 v) {
    asm volatile("global_store_dwordx2 %0, %1, off sc0 sc1"
                 :: "v"(p), "v"(v) : "memory");
}

// Monotonic reset-free 2-level grid barrier for 256 co-resident blocks.
// All relaxed agent atomics -> no fences -> L2 contents (weights) survive.
// vmcnt drain makes this wave's coherent ring stores globally visible first.
__device__ __forceinline__ void grid_sync(unsigned* cnt_x, unsigned* cnt_g,
                                          int grp, unsigned k)
{
    asm volatile("s_waitcnt vmcnt(0)" ::: "memory");
    __syncthreads();
    if (threadIdx.x == 0) {
        unsigned a = __hip_atomic_fetch_add(cnt_x + grp, 1u,
                         __ATOMIC_RELAXED, __HIP_MEMORY_SCOPE_AGENT);
        if (a == 32u * k - 1u)
            __hip_atomic_fetch_add(cnt_g, 1u,
                __ATOMIC_RELAXED, __HIP_MEMORY_SCOPE_AGENT);
        while (__hip_atomic_load(cnt_g, __ATOMIC_RELAXED,
                                 __HIP_MEMORY_SCOPE_AGENT) < 8u * k)
            __builtin_amdgcn_s_sleep(2);
    }
    __syncthreads();
}

// ---------------------------------------------------------------------------
// One ConvLSTM cell phase. Block = 8x8 px tile, all 256 gate rows, persistent.
// 8 waves = 4 hg x 2 px-halves; wave = 64 gate rows x 32 px; 2 MFMA/iter.
// h interior lives in LDS (hAl/hBl/hOl, [64 px][64 ch]); only the 1-px ring
// crosses blocks (coherent). c lives in thread registers (cr[2][4]).
// ---------------------------------------------------------------------------
template<int NKC, bool CELL1>
__device__ __forceinline__ void cell_phase(
    const _Float16* __restrict__ xt,      // CELL1 only: xh [px][8] (cached)
    const _Float16* hAl,                  // LDS interior: cell1 h0(t-1), cell2 h0(t)
    const _Float16* __restrict__ ringA,   // coherent ring for hA
    const _Float16* hBl,                  // CELL2 only: LDS interior h1(t-1)
    const _Float16* __restrict__ ringB,   // CELL2 only: ring h1(t-1)
    const _Float16* __restrict__ Wp,      // packed [NKC][9][8 mf][512] (L2-resident)
    const float* bias_lds,                // 256 biases in LDS
    float (&cr)[2][4],                    // this thread's 8 c values (registers)
    _Float16* hOl,                        // LDS interior out
    _Float16* __restrict__ ringO,         // coherent ring out
    _Float16* stage, int y0, int x0)
{
    constexpr int NCH = 2 * NKC, NCHP = NCH + 1;
    const int tid = threadIdx.x;

    // ---- stage halo 10x10 px x NCH chunks (interior from LDS, ring coherent) ----
    for (int i = tid; i < 100 * NCH; i += 512) {
        int ks, pc;
        if constexpr (NCH == 16) { ks = i & 15; pc = i >> 4; }
        else                     { ks = i % NCH; pc = i / NCH; }
        int r = pc / 10, c = pc - r * 10;
        int gy = y0 - 1 + r, gx = x0 - 1 + c;
        half8 v = {0, 0, 0, 0, 0, 0, 0, 0};
        if (gy >= 0 && gy < HW && gx >= 0 && gx < HW) {
            int px = gy * HW + gx;
            bool inter = (unsigned)(r - 1) < 8u && (unsigned)(c - 1) < 8u;
            int lpx = (r - 1) * 8 + (c - 1);
            if constexpr (CELL1) {
                if (ks == 0)      v = *(const half8*)(xt + (size_t)px * 8);
                else if (ks >= 2) {
                    int ch = (ks - 2) * 8;
                    if (inter) v = *(const half8*)(hAl + lpx * 64 + ch);
                    else       v = ld_coh16(ringA + (size_t)px * 64 + ch);
                }
                // ks==1: zero (weights for k 8..15 are zero)
            } else {
                const _Float16* hl = (ks < 8) ? hAl : hBl;
                const _Float16* rg = (ks < 8) ? ringA : ringB;
                int ch = (ks & 7) * 8;
                if (inter) v = *(const half8*)(hl + lpx * 64 + ch);
                else       v = ld_coh16(rg + (size_t)px * 64 + ch);
            }
        }
        *(half8*)(stage + ((size_t)pc * NCHP + ks) * 8) = v;
    }
    __syncthreads();

    const int lane = tid & 63;
    const int w    = tid >> 6;
    const int hg   = w >> 1;
    const int ph   = w & 1;
    const int l5   = lane >> 5;
    const int col  = lane & 31;
    const int rl   = col >> 3, cl = col & 7;

    floatx16 acc0 = {0,0,0,0,0,0,0,0,0,0,0,0,0,0,0,0};
    floatx16 acc1 = {0,0,0,0,0,0,0,0,0,0,0,0,0,0,0,0};

    const _Float16* wbase = Wp + hg * 1024 + lane * 8;
    #pragma unroll
    for (int kc = 0; kc < NKC; ++kc) {
        half8 a[9][2];
        const _Float16* ap = wbase + (size_t)kc * 9 * 4096;
        #pragma unroll
        for (int tap = 0; tap < 9; ++tap) {
            a[tap][0] = *(const half8*)(ap + tap * 4096);
            a[tap][1] = *(const half8*)(ap + tap * 4096 + 512);
        }
        const int chunk = kc * 2 + l5;
        #pragma unroll
        for (int tap = 0; tap < 9; ++tap) {
            const int dy = tap / 3, dx = tap - dy * 3;
            const int pc = (4 * ph + rl + dy) * 10 + cl + dx;
            half8 b = *(const half8*)(stage + ((size_t)pc * NCHP + chunk) * 8);
            acc0 = __builtin_amdgcn_mfma_f32_32x32x16_f16(a[tap][0], b, acc0, 0, 0, 0);
            acc1 = __builtin_amdgcn_mfma_f32_32x32x16_f16(a[tap][1], b, acc1, 0, 0, 0);
        }
    }

    // ---- LSTM epilogue. rr=(r&3)+8*(r>>2)+4*l5; rr<16 -> i/o, rr>=16 -> f/g.
    const int lr = 4 * ph + rl, lc = cl;
    const int gy = y0 + lr, gx = x0 + lc;
    const bool bdry = (lr == 0) | (lr == 7) | (lc == 0) | (lc == 7);
    const size_t pxo = (size_t)(gy * HW + gx) * 64;
    const int lpo = (lr * 8 + lc) * 64;
    #pragma unroll
    for (int q = 0; q < 2; ++q) {
        int ch0 = hg * 16 + 4 * l5 + 8 * q;
        float bi[4], bf[4], bo[4], bg[4];
        #pragma unroll
        for (int lo = 0; lo < 4; ++lo) {
            bi[lo] = bias_lds[      ch0 + lo];
            bf[lo] = bias_lds[ 64 + ch0 + lo];
            bo[lo] = bias_lds[128 + ch0 + lo];
            bg[lo] = bias_lds[192 + ch0 + lo];
        }
        half4 hn;
        #pragma unroll
        for (int lo = 0; lo < 4; ++lo) {
            int r0_ = 4 * q + lo;
            int r1_ = 8 + 4 * q + lo;
            float iv = sigf(acc0[r0_] + bi[lo]);
            float fv = sigf(acc0[r1_] + bf[lo]);
            float ov = sigf(acc1[r0_] + bo[lo]);
            float gv = tanhf(acc1[r1_] + bg[lo]);
            float cv = fv * cr[q][lo] + iv * gv;
            cr[q][lo] = cv;
            hn[lo] = (_Float16)(ov * tanhf(cv));
        }
        *(half4*)(hOl + lpo + ch0) = hn;
        if (bdry) st_coh8(ringO + pxo + ch0, hn);
    }
}

// Readout 64->1 conv for this block's 8x8 tile. Stage h1 (LDS interior +
// coherent ring) into rstage, then 8 threads/px + shfl reduce.
__device__ __forceinline__ void readout_phase(
    const _Float16* h1l, const _Float16* __restrict__ h1_ring,
    const float* wl, float brv, float* __restrict__ yout,
    int y0, int x0, _Float16* rstage)
{
    const int tid = threadIdx.x;
    __syncthreads();                       // stage buffer reuse safety
    for (int i = tid; i < 800; i += 512) {
        int ks = i & 7, pc = i >> 3;
        int r = pc / 10, c = pc - r * 10;
        int gy = y0 - 1 + r, gx = x0 - 1 + c;
        half8 v = {0, 0, 0, 0, 0, 0, 0, 0};
        if (gy >= 0 && gy < HW && gx >= 0 && gx < HW) {
            bool inter = (unsigned)(r - 1) < 8u && (unsigned)(c - 1) < 8u;
            if (inter) v = *(const half8*)(h1l + ((r - 1) * 8 + (c - 1)) * 64 + ks * 8);
            else       v = ld_coh16(h1_ring + (size_t)(gy * HW + gx) * 64 + ks * 8);
        }
        *(half8*)(rstage + (size_t)i * 8) = v;
    }
    __syncthreads();

    const int sub = tid & 7;
    const int p   = tid >> 3;
    const int pr  = p >> 3, pcc = p & 7;
    float s = 0.0f;
    #pragma unroll
    for (int dy = 0; dy < 3; ++dy)
        #pragma unroll
        for (int dx = 0; dx < 3; ++dx) {
            int pc = (pr + dy) * 10 + (pcc + dx);
            half8 hv = *(const half8*)(rstage + ((size_t)pc * 8 + sub) * 8);
            int tap = dy * 3 + dx;
            #pragma unroll
            for (int j = 0; j < 8; ++j)
                s += wl[(sub * 8 + j) * 9 + tap] * (float)hv[j];
        }
    s += __shfl_xor(s, 1);
    s += __shfl_xor(s, 2);
    s += __shfl_xor(s, 4);
    if (sub == 0) yout[(y0 + pr) * HW + (x0 + pcc)] = s + brv;
}

__global__ __launch_bounds__(512, 2)
void mega(const _Float16* __restrict__ xh,
          const _Float16* __restrict__ Wp0, const _Float16* __restrict__ Wp1,
          const float* __restrict__ b0g, const float* __restrict__ b1g,
          const float* __restrict__ Wr, const float* __restrict__ br,
          _Float16* __restrict__ h0a, _Float16* __restrict__ h0b,
          _Float16* __restrict__ h1a, _Float16* __restrict__ h1b,
          float* __restrict__ y, unsigned* cnt_x, unsigned* cnt_g)
{
    __shared__ __align__(16) _Float16 stage[100 * 17 * 8];   // 27.2 KB
    __shared__ __align__(16) _Float16 h0l[64 * 64];          // 8 KB, persists
    __shared__ __align__(16) _Float16 h1l[64 * 64];          // 8 KB, persists
    __shared__ float wl[576];
    __shared__ float blds[512];

    const int tid = threadIdx.x;
    for (int i = tid; i < 576; i += 512) wl[i] = Wr[i];
    for (int i = tid; i < 512; i += 512) blds[i] = (i < 256) ? b0g[i] : b1g[i - 256];
    {   // zero initial h state (t=0 recurrent inputs)
        half8 z = {0, 0, 0, 0, 0, 0, 0, 0};
        *(half8*)(h0l + tid * 8) = z;
        *(half8*)(h1l + tid * 8) = z;
    }
    float c0r[2][4] = {{0, 0, 0, 0}, {0, 0, 0, 0}};
    float c1r[2][4] = {{0, 0, 0, 0}, {0, 0, 0, 0}};
    const float brv = br[0];

    // XCD-chunked tile map: 16x16 tiles of 8x8 px; each XCD owns a 4x8 region.
    const int bid = blockIdx.x;
    const int grp = bid & 7, lid = bid >> 3;
    const int ty = (grp >> 1) * 4 + (lid >> 3);
    const int tx = (grp & 1) * 8 + (lid & 7);
    const int y0 = ty * 8, x0 = tx * 8;
    __syncthreads();

    #pragma unroll 1
    for (int t = 0; t < 32; ++t) {
        const _Float16* xt = xh + (size_t)t * NPIX * 8;
        _Float16* h0r = (t & 1) ? h0b : h0a;
        _Float16* h0w = (t & 1) ? h0a : h0b;
        _Float16* h1r = (t & 1) ? h1b : h1a;
        _Float16* h1w = (t & 1) ? h1a : h1b;

        cell_phase<5, true>(xt, h0l, h0r, nullptr, nullptr, Wp0, blds,
                            c0r, h0l, h0w, stage, y0, x0);
        if (t > 0) readout_phase(h1l, h1r, wl, brv,
                                 y + (size_t)(t - 1) * NPIX, y0, x0, stage);
        grid_sync(cnt_x, cnt_g, grp, 2u * t + 1u);

        cell_phase<8, false>(nullptr, h0l, h0w, h1l, h1r, Wp1, blds + 256,
                             c1r, h1l, h1w, stage, y0, x0);
        grid_sync(cnt_x, cnt_g, grp, 2u * t + 2u);
    }
    readout_phase(h1l, h1a, wl, brv, y + (size_t)31 * NPIX, y0, x0, stage);
}

// ---------------------------------------------------------------------------
// Weight repack (unchanged layout): W [256][CIN_W][3][3] fp32 ->
// Wp [NKC][9][8 mf][64 lanes][8] fp16. k = kc*16 + (lane>>5)*8 + j.
// ---------------------------------------------------------------------------
__global__ void pack_w(const float* __restrict__ W, _Float16* __restrict__ Wp,
                       int NKC, int CIN_W, int cell1, int total)
{
    int idx = blockIdx.x * 256 + threadIdx.x;
    if (idx >= total) return;
    int j  = idx & 7;
    int l  = (idx >> 3) & 63;
    int mf = (idx >> 9) & 7;
    int kt = idx >> 12;                 // kc*9 + tap
    int tap = kt % 9, kc = kt / 9;
    int rr = l & 31, l5 = l >> 5;
    int f = mf & 1, hg = mf >> 1;
    int gate = f * 2 + (rr >> 4);
    int hid  = hg * 16 + (rr & 15);
    int o = gate * 64 + hid;
    int k = kc * 16 + l5 * 8 + j;
    int cin;
    if (cell1) cin = (k < 4) ? k : ((k >= 16 && k < 80) ? (k - 12) : -1);
    else       cin = k;
    float v = (cin >= 0) ? W[((size_t)o * CIN_W + cin) * 9 + tap] : 0.0f;
    Wp[idx] = (_Float16)v;
}

// x [32][4][128][128] fp32 -> xh [32][px][8] fp16 (ch 0-3 real, 4-7 zero)
__global__ void xconv(const float* __restrict__ x, _Float16* __restrict__ xh)
{
    int idx = blockIdx.x * 256 + threadIdx.x;       // 524288
    int t = idx >> 14, px = idx & 16383;
    const float* xs = x + (size_t)t * 4 * NPIX + px;
    half8 v = {0, 0, 0, 0, 0, 0, 0, 0};
    v[0] = (_Float16)xs[0];
    v[1] = (_Float16)xs[NPIX];
    v[2] = (_Float16)xs[2 * NPIX];
    v[3] = (_Float16)xs[3 * NPIX];
    *(half8*)(xh + (size_t)idx * 8) = v;
}

extern "C" void kernel_launch(void* const* d_in, const int* in_sizes, int n_in,
                              void* d_out, int out_size, void* d_ws, size_t ws_size,
                              hipStream_t stream)
{
    const float* x  = (const float*)d_in[0];
    const float* W0 = (const float*)d_in[1];
    const float* b0 = (const float*)d_in[2];
    const float* W1 = (const float*)d_in[3];
    const float* b1 = (const float*)d_in[4];
    const float* Wr = (const float*)d_in[5];
    const float* br = (const float*)d_in[6];
    float* y = (float*)d_out;

    char* ws = (char*)d_ws;
    _Float16* h0a = (_Float16*)(ws);                    // 2 MB ring (coh)
    _Float16* h1a = (_Float16*)(ws + (2u << 20));       // 2 MB
    _Float16* h0b = (_Float16*)(ws + (4u << 20));       // 2 MB
    _Float16* h1b = (_Float16*)(ws + (6u << 20));       // 2 MB
    _Float16* xh  = (_Float16*)(ws + (8u << 20));       // 8 MB
    _Float16* Wp0 = (_Float16*)(ws + (16u << 20));      // 360 KB
    _Float16* Wp1 = (_Float16*)(ws + (17u << 20));      // 576 KB
    unsigned* cnt = (unsigned*)(ws + (18u << 20));      // 64 B

    // zero ring buffers (t=0 recurrent reads) + barrier counters
    hipMemsetAsync(ws, 0, (8u << 20), stream);
    hipMemsetAsync(cnt, 0, 64, stream);

    pack_w<<<dim3((184320 + 255) / 256), 256, 0, stream>>>(W0, Wp0, 5, 68, 1, 184320);
    pack_w<<<dim3((294912 + 255) / 256), 256, 0, stream>>>(W1, Wp1, 8, 128, 0, 294912);
    xconv<<<dim3(2048), 256, 0, stream>>>(x, xh);

    mega<<<dim3(256), 512, 0, stream>>>(xh, Wp0, Wp1, b0, b1, Wr, br,
                                        h0a, h0b, h1a, h1b, y, cnt, cnt + 8);
}

// Round 8
// 2336.837 us; speedup vs baseline: 3.0560x; 1.8083x over previous
//
#include <hip/hip_runtime.h>
#include <cstdint>
#include <cmath>

#define HW 128
#define NPIX (HW * HW)

typedef _Float16 half8 __attribute__((ext_vector_type(8)));
typedef _Float16 half4 __attribute__((ext_vector_type(4)));
typedef float floatx16 __attribute__((ext_vector_type(16)));

__device__ __forceinline__ float sigf(float x) { return 1.0f / (1.0f + expf(-x)); }

// device-coherent write-through stores (visible at IF; no dirty L2 lines)
__device__ __forceinline__ void st_coh8(_Float16* p, half4 v) {
    asm volatile("global_store_dwordx2 %0, %1, off sc0 sc1"
                 :: "v"(p), "v"(v) : "memory");
}
__device__ __forceinline__ void st_coh4(float* p, float v) {
    asm volatile("global_store_dword %0, %1, off sc0 sc1"
                 :: "v"(p), "v"(v) : "memory");
}

// Monotonic reset-free 2-level grid barrier for 256 co-resident blocks.
// Relaxed agent atomics only; vmcnt drain publishes this block's sc1 stores.
__device__ __forceinline__ void grid_sync(unsigned* cnt_x, unsigned* cnt_g,
                                          int grp, unsigned k)
{
    asm volatile("s_waitcnt vmcnt(0)" ::: "memory");
    __syncthreads();
    if (threadIdx.x == 0) {
        unsigned a = __hip_atomic_fetch_add(cnt_x + grp, 1u,
                         __ATOMIC_RELAXED, __HIP_MEMORY_SCOPE_AGENT);
        if (a == 32u * k - 1u)
            __hip_atomic_fetch_add(cnt_g, 1u,
                __ATOMIC_RELAXED, __HIP_MEMORY_SCOPE_AGENT);
        while (__hip_atomic_load(cnt_g, __ATOMIC_RELAXED,
                                 __HIP_MEMORY_SCOPE_AGENT) < 8u * k)
            __builtin_amdgcn_s_sleep(2);
    }
    __syncthreads();
}

// ---------------------------------------------------------------------------
// Cell phase. Group (bid&31) = 16x32 px tile; this block (s = bid>>5) computes
// gate rows [s*32, s*32+32) (= all 4 gates of hid s*8..s*8+7) for all 512 px.
// Weights live in LDS (wlds). B staged per-kc-slice (2 chunks x 612 halo px),
// double-buffered. Wave w: tile rows {2w, 2w+1}; acc[pos] = 32 gch x 32 px.
// h reads: plain cached loads (valid after agent-acquire fence).
// ---------------------------------------------------------------------------
template<int NKC, int CELL>
__device__ __forceinline__ void cell_phase(
    const _Float16* __restrict__ xt,    // CELL 0 only: xh [px][8]
    const _Float16* __restrict__ hA,    // CELL0: h0(t-1); CELL1: h0(t)
    const _Float16* __restrict__ hB,    // CELL1 only: h1(t-1)
    const _Float16* wlds,               // LDS weight slice [NKC][9][512]
    const float* blds,                  // LDS bias [2][4 gate][8 hid]
    float (&cr)[2][4],                  // c in registers
    _Float16* __restrict__ hOut,        // h out [px][64], sc1 stores
    _Float16* sbuf,                     // LDS [2 buf][2 chunk][612][8]
    int y0, int x0, int s)
{
    const int tid  = threadIdx.x;
    const int lane = tid & 63;
    const int w    = tid >> 6;
    const int cl   = lane & 31;
    const int l5   = lane >> 5;

    auto stage = [&](int kc, int b) {
        #pragma unroll
        for (int e0 = 0; e0 < 3; ++e0) {
            int e = tid + e0 * 512;
            if (e < 1224) {
                int ch16 = e & 1, pc = e >> 1;
                int r = pc / 34, c = pc - r * 34;
                int gy = y0 - 1 + r, gx = x0 - 1 + c;
                half8 v = {0, 0, 0, 0, 0, 0, 0, 0};
                if (gy >= 0 && gy < HW && gx >= 0 && gx < HW) {
                    int px = gy * HW + gx;
                    if (CELL == 0) {
                        if (kc == 0) { if (ch16 == 0) v = *(const half8*)(xt + (size_t)px * 8); }
                        else v = *(const half8*)(hA + (size_t)px * 64 + (kc - 1) * 16 + ch16 * 8);
                    } else {
                        v = (kc < 4) ? *(const half8*)(hA + (size_t)px * 64 + kc * 16 + ch16 * 8)
                                     : *(const half8*)(hB + (size_t)px * 64 + (kc - 4) * 16 + ch16 * 8);
                    }
                }
                *(half8*)(sbuf + ((size_t)(b * 2 + ch16) * 612 + pc) * 8) = v;
            }
        }
    };

    floatx16 acc[2];
    #pragma unroll
    for (int p_ = 0; p_ < 2; ++p_)
        #pragma unroll
        for (int i = 0; i < 16; ++i) acc[p_][i] = 0.0f;

    stage(0, 0);
    __syncthreads();
    #pragma unroll 1
    for (int kc = 0; kc < NKC; ++kc) {
        if (kc + 1 < NKC) stage(kc + 1, (kc + 1) & 1);
        const _Float16* wk = wlds + (size_t)(kc * 9) * 512 + lane * 8;
        const int bb = (kc & 1) * 2 + l5;
        #pragma unroll
        for (int tap = 0; tap < 9; ++tap) {
            const int dy = tap / 3, dx = tap - dy * 3;
            half8 a = *(const half8*)(wk + tap * 512);
            #pragma unroll
            for (int pos = 0; pos < 2; ++pos) {
                int pc = (2 * w + pos + dy) * 34 + cl + dx;
                half8 bf = *(const half8*)(sbuf + ((size_t)bb * 612 + pc) * 8);
                acc[pos] = __builtin_amdgcn_mfma_f32_32x32x16_f16(a, bf, acc[pos], 0, 0, 0);
            }
        }
        __syncthreads();
    }

    // Epilogue. C/D: col=lane&31 -> px col; reg r=g*4+j -> gate g, hid s*8+4*l5+j.
    #pragma unroll
    for (int pos = 0; pos < 2; ++pos) {
        const int p  = 2 * w + pos;
        const int px = (y0 + p) * HW + x0 + cl;
        half4 hn;
        #pragma unroll
        for (int j = 0; j < 4; ++j) {
            const int bo = CELL * 32 + 4 * l5 + j;
            float iv = sigf(acc[pos][     j] + blds[bo]);
            float fv = sigf(acc[pos][ 4 + j] + blds[bo + 8]);
            float ov = sigf(acc[pos][ 8 + j] + blds[bo + 16]);
            float gv = tanhf(acc[pos][12 + j] + blds[bo + 24]);
            float cv = fv * cr[pos][j] + iv * gv;
            cr[pos][j] = cv;
            hn[j] = (_Float16)(ov * tanhf(cv));
        }
        st_coh8(hOut + (size_t)px * 64 + s * 8 + 4 * l5, hn);
    }
}

// Readout 64->1 conv. Block s handles patch s (8x8) of its group tile.
__device__ __forceinline__ void readout_phase(
    const _Float16* __restrict__ h1, const float* wl, float brv,
    float* __restrict__ yout, int y0, int x0, int s, _Float16* sbuf)
{
    const int tid = threadIdx.x;
    const int py0 = y0 + (s >> 2) * 8, px0 = x0 + (s & 3) * 8;
    __syncthreads();                       // sbuf reuse safety
    for (int e = tid; e < 800; e += 512) {
        int ch8 = e & 7, pc = e >> 3;
        int r = pc / 10, c = pc - r * 10;
        int gy = py0 - 1 + r, gx = px0 - 1 + c;
        half8 v = {0, 0, 0, 0, 0, 0, 0, 0};
        if (gy >= 0 && gy < HW && gx >= 0 && gx < HW)
            v = *(const half8*)(h1 + (size_t)(gy * HW + gx) * 64 + ch8 * 8);
        *(half8*)(sbuf + ((size_t)pc * 8 + ch8) * 8) = v;
    }
    __syncthreads();

    const int sub = tid & 7;
    const int p   = tid >> 3;
    const int pr  = p >> 3, pcc = p & 7;
    float sacc = 0.0f;
    #pragma unroll
    for (int dy = 0; dy < 3; ++dy)
        #pragma unroll
        for (int dx = 0; dx < 3; ++dx) {
            int pc = (pr + dy) * 10 + (pcc + dx);
            half8 hv = *(const half8*)(sbuf + ((size_t)pc * 8 + sub) * 8);
            int tap = dy * 3 + dx;
            #pragma unroll
            for (int j = 0; j < 8; ++j)
                sacc += wl[(sub * 8 + j) * 9 + tap] * (float)hv[j];
        }
    sacc += __shfl_xor(sacc, 1);
    sacc += __shfl_xor(sacc, 2);
    sacc += __shfl_xor(sacc, 4);
    if (sub == 0) st_coh4(yout + (py0 + pr) * HW + px0 + pcc, sacc + brv);
}

// LDS map (dynamic, 161536 B):
//   wlds   @ 0      : 119808 B  (cell1 23040 halfs + cell2 36864 halfs)
//   sbuf   @ 119808 : 39168 B   (2 buf x 2 chunk x 612 px x 16 B)
//   wl     @ 158976 : 2304 B    (576 f32 readout weights)
//   blds   @ 161280 : 256 B     (64 f32 biases for this slice)
__global__ __launch_bounds__(512, 2)
void mega(const _Float16* __restrict__ xh, const _Float16* __restrict__ WpG,
          const float* __restrict__ b0g, const float* __restrict__ b1g,
          const float* __restrict__ Wr, const float* __restrict__ br,
          _Float16* __restrict__ h0a, _Float16* __restrict__ h0b,
          _Float16* __restrict__ h1a, _Float16* __restrict__ h1b,
          float* __restrict__ y, unsigned* cnt_x, unsigned* cnt_g)
{
    extern __shared__ __align__(16) char dyn[];
    _Float16* wlds = (_Float16*)dyn;
    _Float16* sbuf = (_Float16*)(dyn + 119808);
    float*    wl   = (float*)(dyn + 158976);
    float*    blds = (float*)(dyn + 161280);

    const int tid = threadIdx.x;
    const int bid = blockIdx.x;
    const int s = bid >> 5, g = bid & 31;
    const int y0 = (g >> 2) * 16, x0 = (g & 3) * 32;
    const int grp = bid & 7;

    // one-time: weight slice + readout weights + biases into LDS
    const half8* wsrc = (const half8*)(WpG + (size_t)s * 59904);
    for (int i = tid; i < 7488; i += 512) ((half8*)wlds)[i] = wsrc[i];
    for (int i = tid; i < 576; i += 512) wl[i] = Wr[i];
    if (tid < 64) {
        int cell = tid >> 5, gj = tid & 31;
        int gate = gj >> 3, h8 = gj & 7;
        blds[tid] = (cell ? b1g : b0g)[gate * 64 + s * 8 + h8];
    }
    const float brv = br[0];
    float c0r[2][4] = {{0, 0, 0, 0}, {0, 0, 0, 0}};
    float c1r[2][4] = {{0, 0, 0, 0}, {0, 0, 0, 0}};
    __syncthreads();
    __builtin_amdgcn_fence(__ATOMIC_ACQUIRE, "agent");

    #pragma unroll 1
    for (int t = 0; t < 32; ++t) {
        const _Float16* xt = xh + (size_t)t * NPIX * 8;
        _Float16* h0r = (t & 1) ? h0b : h0a;
        _Float16* h0w = (t & 1) ? h0a : h0b;
        _Float16* h1r = (t & 1) ? h1b : h1a;
        _Float16* h1w = (t & 1) ? h1a : h1b;

        cell_phase<5, 0>(xt, h0r, nullptr, wlds, blds, c0r, h0w, sbuf, y0, x0, s);
        if (t > 0) readout_phase(h1r, wl, brv, y + (size_t)(t - 1) * NPIX, y0, x0, s, sbuf);
        grid_sync(cnt_x, cnt_g, grp, 2u * t + 1u);
        __builtin_amdgcn_fence(__ATOMIC_ACQUIRE, "agent");   // inv L1+L2 -> fresh h

        cell_phase<8, 1>(nullptr, h0w, h1r, wlds + 23040, blds, c1r, h1w, sbuf, y0, x0, s);
        grid_sync(cnt_x, cnt_g, grp, 2u * t + 2u);
        __builtin_amdgcn_fence(__ATOMIC_ACQUIRE, "agent");
    }
    readout_phase(h1a, wl, brv, y + (size_t)31 * NPIX, y0, x0, s, sbuf);
}

// ---------------------------------------------------------------------------
// Weight repack: W [256][CIN_W][3][3] fp32 -> WpG [8 s][cell][kc][tap][512] fp16.
// A row rr (=lane&31): gate = rr>>3, hid = s*8 + (rr&7); k = kc*16 + (l>>5)*8 + j.
// ---------------------------------------------------------------------------
__global__ void pack_w(const float* __restrict__ W, _Float16* __restrict__ Wp,
                       int NKC, int CIN_W, int cell1, int base, int total)
{
    int idx = blockIdx.x * 256 + threadIdx.x;
    if (idx >= total) return;
    int j = idx & 7, l = (idx >> 3) & 63;
    int rest = idx >> 9;
    int tap = rest % 9;
    int kt  = rest / 9;
    int kc = kt % NKC, s = kt / NKC;
    int rr = l & 31, l5 = l >> 5;
    int o = (rr >> 3) * 64 + s * 8 + (rr & 7);
    int k = kc * 16 + l5 * 8 + j;
    int cin = cell1 ? ((k < 4) ? k : ((k >= 16 && k < 80) ? k - 12 : -1)) : k;
    float v = (cin >= 0) ? W[((size_t)o * CIN_W + cin) * 9 + tap] : 0.0f;
    Wp[(size_t)s * 59904 + base + (size_t)(kc * 9 + tap) * 512 + l * 8 + j] = (_Float16)v;
}

// x [32][4][128][128] fp32 -> xh [32][px][8] fp16 (ch 0-3 real, 4-7 zero)
__global__ void xconv(const float* __restrict__ x, _Float16* __restrict__ xh)
{
    int idx = blockIdx.x * 256 + threadIdx.x;       // 524288
    int t = idx >> 14, px = idx & 16383;
    const float* xs = x + (size_t)t * 4 * NPIX + px;
    half8 v = {0, 0, 0, 0, 0, 0, 0, 0};
    v[0] = (_Float16)xs[0];
    v[1] = (_Float16)xs[NPIX];
    v[2] = (_Float16)xs[2 * NPIX];
    v[3] = (_Float16)xs[3 * NPIX];
    *(half8*)(xh + (size_t)idx * 8) = v;
}

extern "C" void kernel_launch(void* const* d_in, const int* in_sizes, int n_in,
                              void* d_out, int out_size, void* d_ws, size_t ws_size,
                              hipStream_t stream)
{
    const float* x  = (const float*)d_in[0];
    const float* W0 = (const float*)d_in[1];
    const float* b0 = (const float*)d_in[2];
    const float* W1 = (const float*)d_in[3];
    const float* b1 = (const float*)d_in[4];
    const float* Wr = (const float*)d_in[5];
    const float* br = (const float*)d_in[6];
    float* y = (float*)d_out;

    char* ws = (char*)d_ws;
    _Float16* h0a = (_Float16*)(ws);                    // 2 MB
    _Float16* h1a = (_Float16*)(ws + (2u << 20));       // 2 MB
    _Float16* h0b = (_Float16*)(ws + (4u << 20));       // 2 MB
    _Float16* h1b = (_Float16*)(ws + (6u << 20));       // 2 MB
    _Float16* xh  = (_Float16*)(ws + (8u << 20));       // 8 MB
    _Float16* WpG = (_Float16*)(ws + (16u << 20));      // 936 KB
    unsigned* cnt = (unsigned*)(ws + (17u << 20));      // 64 B

    // zero t=0 recurrent state (h0a, h1a; h0b/h1b written before read) + counters
    hipMemsetAsync(ws, 0, (8u << 20), stream);
    hipMemsetAsync(cnt, 0, 64, stream);

    pack_w<<<dim3((184320 + 255) / 256), 256, 0, stream>>>(W0, WpG, 5, 68, 1, 0, 184320);
    pack_w<<<dim3((294912 + 255) / 256), 256, 0, stream>>>(W1, WpG, 8, 128, 0, 23040, 294912);
    xconv<<<dim3(2048), 256, 0, stream>>>(x, xh);

    hipFuncSetAttribute(reinterpret_cast<const void*>(mega),
                        hipFuncAttributeMaxDynamicSharedMemorySize, 161536);
    mega<<<dim3(256), 512, 161536, stream>>>(xh, WpG, b0, b1, Wr, br,
                                             h0a, h0b, h1a, h1b, y,
                                             cnt, cnt + 8);
}

// Round 10
// 1886.813 us; speedup vs baseline: 3.7849x; 1.2385x over previous
//
#include <hip/hip_runtime.h>
#include <cstdint>
#include <cmath>

#define HW 128
#define NPIX (HW * HW)

typedef _Float16 half8 __attribute__((ext_vector_type(8)));
typedef _Float16 half4 __attribute__((ext_vector_type(4)));
typedef float floatx16 __attribute__((ext_vector_type(16)));

__device__ __forceinline__ float sigf(float x) { return 1.0f / (1.0f + expf(-x)); }

// device-coherent write-through stores (visible at IF; no dirty L2 lines)
__device__ __forceinline__ void st_coh8(_Float16* p, half4 v) {
    asm volatile("global_store_dwordx2 %0, %1, off sc0 sc1"
                 :: "v"(p), "v"(v) : "memory");
}
__device__ __forceinline__ void st_coh4(float* p, float v) {
    asm volatile("global_store_dword %0, %1, off sc0 sc1"
                 :: "v"(p), "v"(v) : "memory");
}

// Monotonic reset-free 2-level grid barrier for 256 co-resident blocks.
// Counters PADDED: cnt[grp*16] (one 64B granule each), cnt[256] = global.
// Relaxed agent atomics only; vmcnt drain publishes this block's sc1 stores.
__device__ __forceinline__ void grid_sync(unsigned* cnt, int grp, unsigned k)
{
    asm volatile("s_waitcnt vmcnt(0)" ::: "memory");
    __syncthreads();
    if (threadIdx.x == 0) {
        unsigned a = __hip_atomic_fetch_add(cnt + grp * 16, 1u,
                         __ATOMIC_RELAXED, __HIP_MEMORY_SCOPE_AGENT);
        if (a == 32u * k - 1u)
            __hip_atomic_fetch_add(cnt + 256, 1u,
                __ATOMIC_RELAXED, __HIP_MEMORY_SCOPE_AGENT);
        while (__hip_atomic_load(cnt + 256, __ATOMIC_RELAXED,
                                 __HIP_MEMORY_SCOPE_AGENT) < 8u * k)
            __builtin_amdgcn_s_sleep(2);
    }
    __syncthreads();
}

// ---------------------------------------------------------------------------
// Cell phase. Group (bid&31) = 16x32 px tile; block s = bid>>5 computes gate
// rows [s*32, s*32+32) (all 4 gates of hid s*8..s*8+7) for all 512 px.
// Weights in LDS. B staged per-kc-slice, double-buffered, T14 split with
// PLAIN C++ loads (compiler-managed vmcnt -> hazard-free):
//   issue loads(kc+1) -> tap-loop MFMAs(kc) -> ds_write(kc+1) -> sync.
// h reads: plain cached loads (fresh after the agent-acquire fence).
// ---------------------------------------------------------------------------
template<int NKC, int CELL>
__device__ __forceinline__ void cell_phase(
    const _Float16* __restrict__ xt,    // CELL 0 only: xh [px][8]
    const _Float16* __restrict__ hA,    // CELL0: h0(t-1); CELL1: h0(t)
    const _Float16* __restrict__ hB,    // CELL1 only: h1(t-1)
    const _Float16* wlds,               // LDS weight slice [NKC][9][512]
    const float* blds,                  // LDS bias [2][4 gate][8 hid]
    float (&cr)[2][4],                  // c in registers
    _Float16* __restrict__ hOut,        // h out [px][64], sc1 stores
    _Float16* sbuf,                     // LDS [2 buf][2 chunk][612][8]
    int y0, int x0, int s)
{
    const int tid  = threadIdx.x;
    const int lane = tid & 63;
    const int w    = tid >> 6;
    const int cl   = lane & 31;
    const int l5   = lane >> 5;

    half8 vv[3];

    auto stage_load = [&](int kc) {
        #pragma unroll
        for (int e0 = 0; e0 < 3; ++e0) {
            int e = tid + e0 * 512;
            half8 v = {0, 0, 0, 0, 0, 0, 0, 0};
            if (e < 1224) {
                int ch16 = e & 1, pc = e >> 1;
                int r = pc / 34, c = pc - r * 34;
                int gy = y0 - 1 + r, gx = x0 - 1 + c;
                if (gy >= 0 && gy < HW && gx >= 0 && gx < HW) {
                    int px = gy * HW + gx;
                    if (CELL == 0) {
                        if (kc == 0) { if (ch16 == 0) v = *(const half8*)(xt + (size_t)px * 8); }
                        else v = *(const half8*)(hA + (size_t)px * 64 + (kc - 1) * 16 + ch16 * 8);
                    } else {
                        v = (kc < 4) ? *(const half8*)(hA + (size_t)px * 64 + kc * 16 + ch16 * 8)
                                     : *(const half8*)(hB + (size_t)px * 64 + (kc - 4) * 16 + ch16 * 8);
                    }
                }
            }
            vv[e0] = v;
        }
    };
    auto stage_write = [&](int b) {
        #pragma unroll
        for (int e0 = 0; e0 < 3; ++e0) {
            int e = tid + e0 * 512;
            if (e < 1224) {
                int ch16 = e & 1, pc = e >> 1;
                *(half8*)(sbuf + ((size_t)(b * 2 + ch16) * 612 + pc) * 8) = vv[e0];
            }
        }
    };

    floatx16 acc[2];
    #pragma unroll
    for (int p_ = 0; p_ < 2; ++p_)
        #pragma unroll
        for (int i = 0; i < 16; ++i) acc[p_][i] = 0.0f;

    stage_load(0);
    stage_write(0);
    __syncthreads();
    #pragma unroll 1
    for (int kc = 0; kc < NKC; ++kc) {
        if (kc + 1 < NKC) stage_load(kc + 1);
        const _Float16* wk = wlds + (size_t)(kc * 9) * 512 + lane * 8;
        const int bb = (kc & 1) * 2 + l5;
        #pragma unroll
        for (int tap = 0; tap < 9; ++tap) {
            const int dy = tap / 3, dx = tap - dy * 3;
            half8 a = *(const half8*)(wk + tap * 512);
            #pragma unroll
            for (int pos = 0; pos < 2; ++pos) {
                int pc = (2 * w + pos + dy) * 34 + cl + dx;
                half8 bf = *(const half8*)(sbuf + ((size_t)bb * 612 + pc) * 8);
                acc[pos] = __builtin_amdgcn_mfma_f32_32x32x16_f16(a, bf, acc[pos], 0, 0, 0);
            }
        }
        if (kc + 1 < NKC) stage_write((kc + 1) & 1);
        __syncthreads();
    }

    // Epilogue. C/D: col=lane&31 -> px col; reg r=g*4+j -> gate g, hid s*8+4*l5+j.
    #pragma unroll
    for (int pos = 0; pos < 2; ++pos) {
        const int p  = 2 * w + pos;
        const int px = (y0 + p) * HW + x0 + cl;
        half4 hn;
        #pragma unroll
        for (int j = 0; j < 4; ++j) {
            const int bo = CELL * 32 + 4 * l5 + j;
            float iv = sigf(acc[pos][     j] + blds[bo]);
            float fv = sigf(acc[pos][ 4 + j] + blds[bo + 8]);
            float ov = sigf(acc[pos][ 8 + j] + blds[bo + 16]);
            float gv = tanhf(acc[pos][12 + j] + blds[bo + 24]);
            float cv = fv * cr[pos][j] + iv * gv;
            cr[pos][j] = cv;
            hn[j] = (_Float16)(ov * tanhf(cv));
        }
        st_coh8(hOut + (size_t)px * 64 + s * 8 + 4 * l5, hn);
    }
}

// Readout 64->1 conv. Block s handles patch s (8x8) of its group tile.
// T14 split with plain loads: issue -> sync (sbuf reuse) -> ds_write -> sync.
__device__ __forceinline__ void readout_phase(
    const _Float16* __restrict__ h1, const float* wl, float brv,
    float* __restrict__ yout, int y0, int x0, int s, _Float16* sbuf)
{
    const int tid = threadIdx.x;
    const int py0 = y0 + (s >> 2) * 8, px0 = x0 + (s & 3) * 8;

    half8 rv[2];
    #pragma unroll
    for (int e0 = 0; e0 < 2; ++e0) {
        int e = tid + e0 * 512;
        half8 v = {0, 0, 0, 0, 0, 0, 0, 0};
        if (e < 800) {
            int ch8 = e & 7, pc = e >> 3;
            int r = pc / 10, c = pc - r * 10;
            int gy = py0 - 1 + r, gx = px0 - 1 + c;
            if (gy >= 0 && gy < HW && gx >= 0 && gx < HW)
                v = *(const half8*)(h1 + (size_t)(gy * HW + gx) * 64 + ch8 * 8);
        }
        rv[e0] = v;
    }
    __syncthreads();                       // prior sbuf reads complete
    #pragma unroll
    for (int e0 = 0; e0 < 2; ++e0) {
        int e = tid + e0 * 512;
        if (e < 800) {
            int ch8 = e & 7, pc = e >> 3;
            *(half8*)(sbuf + ((size_t)pc * 8 + ch8) * 8) = rv[e0];
        }
    }
    __syncthreads();

    const int sub = tid & 7;
    const int p   = tid >> 3;
    const int pr  = p >> 3, pcc = p & 7;
    float sacc = 0.0f;
    #pragma unroll
    for (int dy = 0; dy < 3; ++dy)
        #pragma unroll
        for (int dx = 0; dx < 3; ++dx) {
            int pc = (pr + dy) * 10 + (pcc + dx);
            half8 hv = *(const half8*)(sbuf + ((size_t)pc * 8 + sub) * 8);
            int tap = dy * 3 + dx;
            #pragma unroll
            for (int j = 0; j < 8; ++j)
                sacc += wl[(sub * 8 + j) * 9 + tap] * (float)hv[j];
        }
    sacc += __shfl_xor(sacc, 1);
    sacc += __shfl_xor(sacc, 2);
    sacc += __shfl_xor(sacc, 4);
    if (sub == 0) st_coh4(yout + (py0 + pr) * HW + px0 + pcc, sacc + brv);
}

// LDS map (dynamic, 161536 B):
//   wlds @ 0      : 119808 B  (cell1 23040 halfs + cell2 36864 halfs)
//   sbuf @ 119808 : 39168 B   (2 buf x 2 chunk x 612 px x 16 B)
//   wl   @ 158976 : 2304 B    (576 f32 readout weights)
//   blds @ 161280 : 256 B     (64 f32 biases for this slice)
__global__ __launch_bounds__(512, 2)
void mega(const _Float16* __restrict__ xh, const _Float16* __restrict__ WpG,
          const float* __restrict__ b0g, const float* __restrict__ b1g,
          const float* __restrict__ Wr, const float* __restrict__ br,
          _Float16* __restrict__ h0a, _Float16* __restrict__ h0b,
          _Float16* __restrict__ h1a, _Float16* __restrict__ h1b,
          float* __restrict__ y, unsigned* cnt)
{
    extern __shared__ __align__(16) char dyn[];
    _Float16* wlds = (_Float16*)dyn;
    _Float16* sbuf = (_Float16*)(dyn + 119808);
    float*    wl   = (float*)(dyn + 158976);
    float*    blds = (float*)(dyn + 161280);

    const int tid = threadIdx.x;
    const int bid = blockIdx.x;
    const int s = bid >> 5, g = bid & 31;
    const int y0 = (g >> 2) * 16, x0 = (g & 3) * 32;
    const int grp = bid & 7;

    // one-time: weight slice + readout weights + biases into LDS
    const half8* wsrc = (const half8*)(WpG + (size_t)s * 59904);
    for (int i = tid; i < 7488; i += 512) ((half8*)wlds)[i] = wsrc[i];
    for (int i = tid; i < 576; i += 512) wl[i] = Wr[i];
    if (tid < 64) {
        int cell = tid >> 5, gj = tid & 31;
        int gate = gj >> 3, h8 = gj & 7;
        blds[tid] = (cell ? b1g : b0g)[gate * 64 + s * 8 + h8];
    }
    const float brv = br[0];
    float c0r[2][4] = {{0, 0, 0, 0}, {0, 0, 0, 0}};
    float c1r[2][4] = {{0, 0, 0, 0}, {0, 0, 0, 0}};
    __syncthreads();
    __builtin_amdgcn_fence(__ATOMIC_ACQUIRE, "agent");

    #pragma unroll 1
    for (int t = 0; t < 32; ++t) {
        const _Float16* xt = xh + (size_t)t * NPIX * 8;
        _Float16* h0r = (t & 1) ? h0b : h0a;
        _Float16* h0w = (t & 1) ? h0a : h0b;
        _Float16* h1r = (t & 1) ? h1b : h1a;
        _Float16* h1w = (t & 1) ? h1a : h1b;

        cell_phase<5, 0>(xt, h0r, nullptr, wlds, blds, c0r, h0w, sbuf, y0, x0, s);
        if (t > 0) readout_phase(h1r, wl, brv, y + (size_t)(t - 1) * NPIX, y0, x0, s, sbuf);
        grid_sync(cnt, grp, 2u * t + 1u);
        __builtin_amdgcn_fence(__ATOMIC_ACQUIRE, "agent");   // inv L1+L2 -> fresh h

        cell_phase<8, 1>(nullptr, h0w, h1r, wlds + 23040, blds, c1r, h1w, sbuf, y0, x0, s);
        grid_sync(cnt, grp, 2u * t + 2u);
        __builtin_amdgcn_fence(__ATOMIC_ACQUIRE, "agent");
    }
    readout_phase(h1a, wl, brv, y + (size_t)31 * NPIX, y0, x0, s, sbuf);
}

// ---------------------------------------------------------------------------
// Weight repack: W [256][CIN_W][3][3] fp32 -> WpG [8 s][cell][kc][tap][512] fp16.
// A row rr (=lane&31): gate = rr>>3, hid = s*8 + (rr&7); k = kc*16 + (l>>5)*8 + j.
// ---------------------------------------------------------------------------
__global__ void pack_w(const float* __restrict__ W, _Float16* __restrict__ Wp,
                       int NKC, int CIN_W, int cell1, int base, int total)
{
    int idx = blockIdx.x * 256 + threadIdx.x;
    if (idx >= total) return;
    int j = idx & 7, l = (idx >> 3) & 63;
    int rest = idx >> 9;
    int tap = rest % 9;
    int kt  = rest / 9;
    int kc = kt % NKC, s = kt / NKC;
    int rr = l & 31, l5 = l >> 5;
    int o = (rr >> 3) * 64 + s * 8 + (rr & 7);
    int k = kc * 16 + l5 * 8 + j;
    int cin = cell1 ? ((k < 4) ? k : ((k >= 16 && k < 80) ? k - 12 : -1)) : k;
    float v = (cin >= 0) ? W[((size_t)o * CIN_W + cin) * 9 + tap] : 0.0f;
    Wp[(size_t)s * 59904 + base + (size_t)(kc * 9 + tap) * 512 + l * 8 + j] = (_Float16)v;
}

// x [32][4][128][128] fp32 -> xh [32][px][8] fp16 (ch 0-3 real, 4-7 zero)
__global__ void xconv(const float* __restrict__ x, _Float16* __restrict__ xh)
{
    int idx = blockIdx.x * 256 + threadIdx.x;       // 524288
    int t = idx >> 14, px = idx & 16383;
    const float* xs = x + (size_t)t * 4 * NPIX + px;
    half8 v = {0, 0, 0, 0, 0, 0, 0, 0};
    v[0] = (_Float16)xs[0];
    v[1] = (_Float16)xs[NPIX];
    v[2] = (_Float16)xs[2 * NPIX];
    v[3] = (_Float16)xs[3 * NPIX];
    *(half8*)(xh + (size_t)idx * 8) = v;
}

extern "C" void kernel_launch(void* const* d_in, const int* in_sizes, int n_in,
                              void* d_out, int out_size, void* d_ws, size_t ws_size,
                              hipStream_t stream)
{
    const float* x  = (const float*)d_in[0];
    const float* W0 = (const float*)d_in[1];
    const float* b0 = (const float*)d_in[2];
    const float* W1 = (const float*)d_in[3];
    const float* b1 = (const float*)d_in[4];
    const float* Wr = (const float*)d_in[5];
    const float* br = (const float*)d_in[6];
    float* y = (float*)d_out;

    char* ws = (char*)d_ws;
    _Float16* h0a = (_Float16*)(ws);                    // 2 MB
    _Float16* h1a = (_Float16*)(ws + (2u << 20));       // 2 MB
    _Float16* h0b = (_Float16*)(ws + (4u << 20));       // 2 MB
    _Float16* h1b = (_Float16*)(ws + (6u << 20));       // 2 MB
    _Float16* xh  = (_Float16*)(ws + (8u << 20));       // 8 MB
    _Float16* WpG = (_Float16*)(ws + (16u << 20));      // 936 KB
    unsigned* cnt = (unsigned*)(ws + (17u << 20));      // 2 KB padded counters

    // zero t=0 recurrent state (h0a, h1a) + barrier counters
    hipMemsetAsync(ws, 0, (8u << 20), stream);
    hipMemsetAsync(cnt, 0, 2048, stream);

    pack_w<<<dim3((184320 + 255) / 256), 256, 0, stream>>>(W0, WpG, 5, 68, 1, 0, 184320);
    pack_w<<<dim3((294912 + 255) / 256), 256, 0, stream>>>(W1, WpG, 8, 128, 0, 23040, 294912);
    xconv<<<dim3(2048), 256, 0, stream>>>(x, xh);

    hipFuncSetAttribute(reinterpret_cast<const void*>(mega),
                        hipFuncAttributeMaxDynamicSharedMemorySize, 161536);
    mega<<<dim3(256), 512, 161536, stream>>>(xh, WpG, b0, b1, Wr, br,
                                             h0a, h0b, h1a, h1b, y, cnt);
}

// Round 11
// 1340.581 us; speedup vs baseline: 5.3271x; 1.4075x over previous
//
#include <hip/hip_runtime.h>
#include <cstdint>
#include <cmath>

#define HW 128
#define NPIX (HW * HW)

typedef _Float16 half8 __attribute__((ext_vector_type(8)));
typedef _Float16 half4 __attribute__((ext_vector_type(4)));
typedef float floatx16 __attribute__((ext_vector_type(16)));

__device__ __forceinline__ float sigf(float x) { return 1.0f / (1.0f + expf(-x)); }

// device-coherent write-through stores (visible at IF; no dirty L2 lines)
__device__ __forceinline__ void st_coh8(_Float16* p, half4 v) {
    asm volatile("global_store_dwordx2 %0, %1, off sc0 sc1"
                 :: "v"(p), "v"(v) : "memory");
}
__device__ __forceinline__ void st_coh4(float* p, float v) {
    asm volatile("global_store_dword %0, %1, off sc0 sc1"
                 :: "v"(p), "v"(v) : "memory");
}

// Monotonic reset-free 2-level grid barrier for 256 co-resident blocks.
// Counters padded to one 64B granule each: cnt[grp*16], cnt[256] = global.
// Relaxed agent atomics only; vmcnt drain publishes this block's sc1 stores.
__device__ __forceinline__ void grid_sync(unsigned* cnt, int grp, unsigned k)
{
    asm volatile("s_waitcnt vmcnt(0)" ::: "memory");
    __syncthreads();
    if (threadIdx.x == 0) {
        unsigned a = __hip_atomic_fetch_add(cnt + grp * 16, 1u,
                         __ATOMIC_RELAXED, __HIP_MEMORY_SCOPE_AGENT);
        if (a == 32u * k - 1u)
            __hip_atomic_fetch_add(cnt + 256, 1u,
                __ATOMIC_RELAXED, __HIP_MEMORY_SCOPE_AGENT);
        while (__hip_atomic_load(cnt + 256, __ATOMIC_RELAXED,
                                 __HIP_MEMORY_SCOPE_AGENT) < 8u * k)
            __builtin_amdgcn_s_sleep(2);
    }
    __syncthreads();
}

// ---------------------------------------------------------------------------
// Cell phase. Group (bid&31) = 16x32 px tile; block s = bid>>5 computes gate
// rows [s*32, s*32+32) (all 4 gates of hid s*8..s*8+7) for all 512 px.
// Weights in LDS. B staged per-kc-slice, double-buffered, T14 split with
// plain C++ loads (compiler-managed vmcnt). Staging addresses PRECOMPUTED
// (t-invariant): spb[e0] = px*64 + ch16*8 (-1 if OOB/pad), slo[e0] = LDS
// half-offset (-1 if no slot). ch16 = tid&1.
// ---------------------------------------------------------------------------
template<int NKC, int CELL>
__device__ __forceinline__ void cell_phase(
    const _Float16* __restrict__ xt,    // CELL 0 only: xh [px][8]
    const _Float16* __restrict__ hA,    // CELL0: h0(t-1); CELL1: h0(t)
    const _Float16* __restrict__ hB,    // CELL1 only: h1(t-1)
    const _Float16* wlds,               // LDS weight slice [NKC][9][512]
    const float* blds,                  // LDS bias [2][4 gate][8 hid]
    float (&cr)[2][4],                  // c in registers
    _Float16* __restrict__ hOut,        // h out [px][64], sc1 stores
    _Float16* sbuf,                     // LDS [2 buf][2 chunk][612][8]
    const int (&spb)[3], const int (&slo)[3], int ch16,
    int y0, int x0, int s)
{
    const int tid  = threadIdx.x;
    const int lane = tid & 63;
    const int w    = tid >> 6;
    const int cl   = lane & 31;
    const int l5   = lane >> 5;

    half8 vv[3];

    auto stage_load = [&](int kc) {
        #pragma unroll
        for (int e0 = 0; e0 < 3; ++e0) {
            half8 v = {0, 0, 0, 0, 0, 0, 0, 0};
            const int pb = spb[e0];
            if (pb >= 0) {
                if (CELL == 0) {
                    if (kc == 0) { if (ch16 == 0) v = *(const half8*)(xt + (pb >> 3)); }
                    else v = *(const half8*)(hA + pb + (kc - 1) * 16);
                } else {
                    v = (kc < 4) ? *(const half8*)(hA + pb + kc * 16)
                                 : *(const half8*)(hB + pb + (kc - 4) * 16);
                }
            }
            vv[e0] = v;
        }
    };
    auto stage_write = [&](int b) {
        #pragma unroll
        for (int e0 = 0; e0 < 3; ++e0) {
            if (slo[e0] >= 0)
                *(half8*)(sbuf + b * 9792 + slo[e0]) = vv[e0];
        }
    };

    floatx16 acc[2];
    #pragma unroll
    for (int p_ = 0; p_ < 2; ++p_)
        #pragma unroll
        for (int i = 0; i < 16; ++i) acc[p_][i] = 0.0f;

    __syncthreads();                       // sbuf reuse safety (prev phase reads)
    stage_load(0);
    stage_write(0);
    __syncthreads();
    #pragma unroll 1
    for (int kc = 0; kc < NKC; ++kc) {
        if (kc + 1 < NKC) stage_load(kc + 1);
        const _Float16* wk = wlds + (size_t)(kc * 9) * 512 + lane * 8;
        const int bb = (kc & 1) * 2 + l5;
        #pragma unroll
        for (int tap = 0; tap < 9; ++tap) {
            const int dy = tap / 3, dx = tap - dy * 3;
            half8 a = *(const half8*)(wk + tap * 512);
            #pragma unroll
            for (int pos = 0; pos < 2; ++pos) {
                int pc = (2 * w + pos + dy) * 34 + cl + dx;
                half8 bf = *(const half8*)(sbuf + ((size_t)bb * 612 + pc) * 8);
                acc[pos] = __builtin_amdgcn_mfma_f32_32x32x16_f16(a, bf, acc[pos], 0, 0, 0);
            }
        }
        if (kc + 1 < NKC) stage_write((kc + 1) & 1);
        __syncthreads();
    }

    // Epilogue. C/D: col=lane&31 -> px col; reg r=g*4+j -> gate g, hid s*8+4*l5+j.
    #pragma unroll
    for (int pos = 0; pos < 2; ++pos) {
        const int p  = 2 * w + pos;
        const int px = (y0 + p) * HW + x0 + cl;
        half4 hn;
        #pragma unroll
        for (int j = 0; j < 4; ++j) {
            const int bo = CELL * 32 + 4 * l5 + j;
            float iv = sigf(acc[pos][     j] + blds[bo]);
            float fv = sigf(acc[pos][ 4 + j] + blds[bo + 8]);
            float ov = sigf(acc[pos][ 8 + j] + blds[bo + 16]);
            float gv = tanhf(acc[pos][12 + j] + blds[bo + 24]);
            float cv = fv * cr[pos][j] + iv * gv;
            cr[pos][j] = cv;
            hn[j] = (_Float16)(ov * tanhf(cv));
        }
        st_coh8(hOut + (size_t)px * 64 + s * 8 + 4 * l5, hn);
    }
}

// Readout 64->1 conv. Block s handles patch s (8x8) of its group tile.
// Staging indices precomputed: rpb (load, -1 OOB), rlo (LDS half-off, -1 none).
__device__ __forceinline__ void readout_phase(
    const _Float16* __restrict__ h1, const float* wl, float brv,
    float* __restrict__ yout, _Float16* sbuf,
    const int (&rpb)[2], const int (&rlo)[2], int ch8, int yidx)
{
    const int tid = threadIdx.x;

    half8 rv[2];
    #pragma unroll
    for (int e0 = 0; e0 < 2; ++e0) {
        half8 v = {0, 0, 0, 0, 0, 0, 0, 0};
        if (rpb[e0] >= 0) v = *(const half8*)(h1 + rpb[e0]);
        rv[e0] = v;
    }
    __syncthreads();                       // prior sbuf reads complete
    #pragma unroll
    for (int e0 = 0; e0 < 2; ++e0)
        if (rlo[e0] >= 0) *(half8*)(sbuf + rlo[e0]) = rv[e0];
    __syncthreads();

    const int sub = tid & 7;
    const int p   = tid >> 3;
    const int pr  = p >> 3, pcc = p & 7;
    float sacc = 0.0f;
    #pragma unroll
    for (int dy = 0; dy < 3; ++dy)
        #pragma unroll
        for (int dx = 0; dx < 3; ++dx) {
            int pc = (pr + dy) * 10 + (pcc + dx);
            half8 hv = *(const half8*)(sbuf + ((size_t)pc * 8 + sub) * 8);
            int tap = dy * 3 + dx;
            #pragma unroll
            for (int j = 0; j < 8; ++j)
                sacc += wl[(sub * 8 + j) * 9 + tap] * (float)hv[j];
        }
    sacc += __shfl_xor(sacc, 1);
    sacc += __shfl_xor(sacc, 2);
    sacc += __shfl_xor(sacc, 4);
    if (sub == 0) st_coh4(yout + yidx, sacc + brv);
}

// LDS map (dynamic, 161536 B):
//   wlds @ 0      : 119808 B  (cell1 23040 halfs + cell2 36864 halfs)
//   sbuf @ 119808 : 39168 B   (2 buf x 2 chunk x 612 px x 16 B)
//   wl   @ 158976 : 2304 B    (576 f32 readout weights)
//   blds @ 161280 : 256 B     (64 f32 biases for this slice)
// Schedule per t: cell1(t); GRID_SYNC; fence; cell2(t); readout(t-1).
// (Barrier-after-cell2 proven redundant: SYNC(t) orders all cell1(t) writes
//  before cell2(t)/readout(t-1)/cell1(t+1); all buffer reuses are in
//  disjoint barrier intervals.)
__global__ __launch_bounds__(512, 2)
void mega(const _Float16* __restrict__ xh, const _Float16* __restrict__ WpG,
          const float* __restrict__ b0g, const float* __restrict__ b1g,
          const float* __restrict__ Wr, const float* __restrict__ br,
          _Float16* __restrict__ h0a, _Float16* __restrict__ h0b,
          _Float16* __restrict__ h1a, _Float16* __restrict__ h1b,
          float* __restrict__ y, unsigned* cnt)
{
    extern __shared__ __align__(16) char dyn[];
    _Float16* wlds = (_Float16*)dyn;
    _Float16* sbuf = (_Float16*)(dyn + 119808);
    float*    wl   = (float*)(dyn + 158976);
    float*    blds = (float*)(dyn + 161280);

    const int tid = threadIdx.x;
    const int bid = blockIdx.x;
    const int s = bid >> 5, g = bid & 31;
    const int y0 = (g >> 2) * 16, x0 = (g & 3) * 32;
    const int grp = bid & 7;

    // one-time: weight slice + readout weights + biases into LDS
    const half8* wsrc = (const half8*)(WpG + (size_t)s * 59904);
    for (int i = tid; i < 7488; i += 512) ((half8*)wlds)[i] = wsrc[i];
    for (int i = tid; i < 576; i += 512) wl[i] = Wr[i];
    if (tid < 64) {
        int cell = tid >> 5, gj = tid & 31;
        int gate = gj >> 3, h8 = gj & 7;
        blds[tid] = (cell ? b1g : b0g)[gate * 64 + s * 8 + h8];
    }
    const float brv = br[0];
    float c0r[2][4] = {{0, 0, 0, 0}, {0, 0, 0, 0}};
    float c1r[2][4] = {{0, 0, 0, 0}, {0, 0, 0, 0}};

    // ---- t-invariant staging index precompute (kills hot-loop div/mod) ----
    const int ch16 = tid & 1;
    int spb[3], slo[3];
    #pragma unroll
    for (int e0 = 0; e0 < 3; ++e0) {
        int e = tid + e0 * 512;
        spb[e0] = -1; slo[e0] = -1;
        if (e < 1224) {
            int pc = e >> 1;
            int r = pc / 34, c = pc - r * 34;
            int gy = y0 - 1 + r, gx = x0 - 1 + c;
            slo[e0] = (ch16 * 612 + pc) * 8;
            if (gy >= 0 && gy < HW && gx >= 0 && gx < HW)
                spb[e0] = (gy * HW + gx) * 64 + ch16 * 8;
        }
    }
    const int ch8 = tid & 7;
    const int py0 = y0 + (s >> 2) * 8, px0 = x0 + (s & 3) * 8;
    int rpb[2], rlo[2];
    #pragma unroll
    for (int e0 = 0; e0 < 2; ++e0) {
        int e = tid + e0 * 512;
        rpb[e0] = -1; rlo[e0] = -1;
        if (e < 800) {
            int pc = e >> 3;
            int r = pc / 10, c = pc - r * 10;
            int gy = py0 - 1 + r, gx = px0 - 1 + c;
            rlo[e0] = (pc * 8 + ch8) * 8;
            if (gy >= 0 && gy < HW && gx >= 0 && gx < HW)
                rpb[e0] = (gy * HW + gx) * 64 + ch8 * 8;
        }
    }
    const int yidx = (py0 + ((tid >> 3) >> 3)) * HW + px0 + ((tid >> 3) & 7);

    __syncthreads();
    __builtin_amdgcn_fence(__ATOMIC_ACQUIRE, "agent");

    #pragma unroll 1
    for (int t = 0; t < 32; ++t) {
        const _Float16* xt = xh + (size_t)t * NPIX * 8;
        _Float16* h0r = (t & 1) ? h0b : h0a;
        _Float16* h0w = (t & 1) ? h0a : h0b;
        _Float16* h1r = (t & 1) ? h1b : h1a;
        _Float16* h1w = (t & 1) ? h1a : h1b;

        cell_phase<5, 0>(xt, h0r, nullptr, wlds, blds, c0r, h0w, sbuf,
                         spb, slo, ch16, y0, x0, s);
        grid_sync(cnt, grp, (unsigned)(t + 1));
        __builtin_amdgcn_fence(__ATOMIC_ACQUIRE, "agent");   // inv L1+L2 -> fresh h

        cell_phase<8, 1>(nullptr, h0w, h1r, wlds + 23040, blds, c1r, h1w, sbuf,
                         spb, slo, ch16, y0, x0, s);
        if (t > 0) readout_phase(h1r, wl, brv, y + (size_t)(t - 1) * NPIX, sbuf,
                                 rpb, rlo, ch8, yidx);
    }
    grid_sync(cnt, grp, 33u);
    __builtin_amdgcn_fence(__ATOMIC_ACQUIRE, "agent");
    readout_phase(h1a, wl, brv, y + (size_t)31 * NPIX, sbuf, rpb, rlo, ch8, yidx);
}

// ---------------------------------------------------------------------------
// Weight repack: W [256][CIN_W][3][3] fp32 -> WpG [8 s][cell][kc][tap][512] fp16.
// A row rr (=lane&31): gate = rr>>3, hid = s*8 + (rr&7); k = kc*16 + (l>>5)*8 + j.
// ---------------------------------------------------------------------------
__global__ void pack_w(const float* __restrict__ W, _Float16* __restrict__ Wp,
                       int NKC, int CIN_W, int cell1, int base, int total)
{
    int idx = blockIdx.x * 256 + threadIdx.x;
    if (idx >= total) return;
    int j = idx & 7, l = (idx >> 3) & 63;
    int rest = idx >> 9;
    int tap = rest % 9;
    int kt  = rest / 9;
    int kc = kt % NKC, s = kt / NKC;
    int rr = l & 31, l5 = l >> 5;
    int o = (rr >> 3) * 64 + s * 8 + (rr & 7);
    int k = kc * 16 + l5 * 8 + j;
    int cin = cell1 ? ((k < 4) ? k : ((k >= 16 && k < 80) ? k - 12 : -1)) : k;
    float v = (cin >= 0) ? W[((size_t)o * CIN_W + cin) * 9 + tap] : 0.0f;
    Wp[(size_t)s * 59904 + base + (size_t)(kc * 9 + tap) * 512 + l * 8 + j] = (_Float16)v;
}

// x [32][4][128][128] fp32 -> xh [32][px][8] fp16 (ch 0-3 real, 4-7 zero)
__global__ void xconv(const float* __restrict__ x, _Float16* __restrict__ xh)
{
    int idx = blockIdx.x * 256 + threadIdx.x;       // 524288
    int t = idx >> 14, px = idx & 16383;
    const float* xs = x + (size_t)t * 4 * NPIX + px;
    half8 v = {0, 0, 0, 0, 0, 0, 0, 0};
    v[0] = (_Float16)xs[0];
    v[1] = (_Float16)xs[NPIX];
    v[2] = (_Float16)xs[2 * NPIX];
    v[3] = (_Float16)xs[3 * NPIX];
    *(half8*)(xh + (size_t)idx * 8) = v;
}

extern "C" void kernel_launch(void* const* d_in, const int* in_sizes, int n_in,
                              void* d_out, int out_size, void* d_ws, size_t ws_size,
                              hipStream_t stream)
{
    const float* x  = (const float*)d_in[0];
    const float* W0 = (const float*)d_in[1];
    const float* b0 = (const float*)d_in[2];
    const float* W1 = (const float*)d_in[3];
    const float* b1 = (const float*)d_in[4];
    const float* Wr = (const float*)d_in[5];
    const float* br = (const float*)d_in[6];
    float* y = (float*)d_out;

    char* ws = (char*)d_ws;
    _Float16* h0a = (_Float16*)(ws);                    // 2 MB
    _Float16* h1a = (_Float16*)(ws + (2u << 20));       // 2 MB
    _Float16* h0b = (_Float16*)(ws + (4u << 20));       // 2 MB
    _Float16* h1b = (_Float16*)(ws + (6u << 20));       // 2 MB
    _Float16* xh  = (_Float16*)(ws + (8u << 20));       // 8 MB
    _Float16* WpG = (_Float16*)(ws + (16u << 20));      // 936 KB
    unsigned* cnt = (unsigned*)(ws + (17u << 20));      // 2 KB padded counters

    // zero t=0 recurrent state (h0a, h1a) + barrier counters
    hipMemsetAsync(ws, 0, (8u << 20), stream);
    hipMemsetAsync(cnt, 0, 2048, stream);

    pack_w<<<dim3((184320 + 255) / 256), 256, 0, stream>>>(W0, WpG, 5, 68, 1, 0, 184320);
    pack_w<<<dim3((294912 + 255) / 256), 256, 0, stream>>>(W1, WpG, 8, 128, 0, 23040, 294912);
    xconv<<<dim3(2048), 256, 0, stream>>>(x, xh);

    hipFuncSetAttribute(reinterpret_cast<const void*>(mega),
                        hipFuncAttributeMaxDynamicSharedMemorySize, 161536);
    mega<<<dim3(256), 512, 161536, stream>>>(xh, WpG, b0, b1, Wr, br,
                                             h0a, h0b, h1a, h1b, y, cnt);
}

// Round 12
// 1235.172 us; speedup vs baseline: 5.7817x; 1.0853x over previous
//
#include <hip/hip_runtime.h>
#include <cstdint>
#include <cmath>

#define HW 128
#define NPIX (HW * HW)

typedef _Float16 half8 __attribute__((ext_vector_type(8)));
typedef _Float16 half4 __attribute__((ext_vector_type(4)));
typedef float floatx16 __attribute__((ext_vector_type(16)));

__device__ __forceinline__ float sigf(float x) {
    return __builtin_amdgcn_rcpf(1.0f + __expf(-x));
}
__device__ __forceinline__ float tanhf_(float x) {
    float cx = fminf(fmaxf(x, -20.0f), 20.0f);
    float e2 = __expf(2.0f * cx);
    return (e2 - 1.0f) * __builtin_amdgcn_rcpf(e2 + 1.0f);
}

// device-coherent write-through stores (visible at IF; no dirty L2 lines)
__device__ __forceinline__ void st_coh8(_Float16* p, half4 v) {
    asm volatile("global_store_dwordx2 %0, %1, off sc0 sc1"
                 :: "v"(p), "v"(v) : "memory");
}
__device__ __forceinline__ void st_coh4(float* p, float v) {
    asm volatile("global_store_dword %0, %1, off sc0 sc1"
                 :: "v"(p), "v"(v) : "memory");
}

// Broadcast grid barrier for 256 co-resident blocks, monotonic instance k.
// Arrival: each block stores k to its OWN 64B-padded slot (parallel, no RMW).
// Block 0's wave 0 polls all 256 slots (4/lane), then stores release = k.
// Others poll release. All relaxed agent atomics -> no cache maintenance.
// vmcnt drain first publishes this block's sc1 h-stores.
__device__ __forceinline__ void grid_sync(unsigned* slots, unsigned* rel,
                                          int bid, unsigned k)
{
    asm volatile("s_waitcnt vmcnt(0)" ::: "memory");
    __syncthreads();
    const int tid = threadIdx.x;
    if (tid == 0)
        __hip_atomic_store(slots + bid * 16, k,
                           __ATOMIC_RELAXED, __HIP_MEMORY_SCOPE_AGENT);
    if (bid == 0) {
        if (tid < 64) {
            #pragma unroll
            for (int j = 0; j < 4; ++j) {
                const unsigned* sp = slots + (tid + j * 64) * 16;
                while (__hip_atomic_load(sp, __ATOMIC_RELAXED,
                                         __HIP_MEMORY_SCOPE_AGENT) < k)
                    __builtin_amdgcn_s_sleep(1);
            }
            if (tid == 0)
                __hip_atomic_store(rel, k,
                                   __ATOMIC_RELAXED, __HIP_MEMORY_SCOPE_AGENT);
        }
    } else if (tid == 0) {
        while (__hip_atomic_load(rel, __ATOMIC_RELAXED,
                                 __HIP_MEMORY_SCOPE_AGENT) < k)
            __builtin_amdgcn_s_sleep(1);
    }
    __syncthreads();
}

// ---------------------------------------------------------------------------
// Cell phase. Group (bid&31) = 16x32 px tile; block s = bid>>5 computes gate
// rows [s*32, s*32+32) (all 4 gates of hid s*8..s*8+7) for all 512 px.
// Weights in LDS. B staged per-kc-slice, double-buffered, T14 split with
// plain C++ loads. Staging addresses precomputed (t-invariant).
// Tap loop: rolling 2-row register cache (bufA/bufB) -> 12 ds_read/kc not 18.
// ---------------------------------------------------------------------------
template<int NKC, int CELL>
__device__ __forceinline__ void cell_phase(
    const _Float16* __restrict__ xt,    // CELL 0 only: xh [px][8]
    const _Float16* __restrict__ hA,    // CELL0: h0(t-1); CELL1: h0(t)
    const _Float16* __restrict__ hB,    // CELL1 only: h1(t-1)
    const _Float16* wlds,               // LDS weight slice [NKC][9][512]
    const float* blds,                  // LDS bias [2][4 gate][8 hid]
    float (&cr)[2][4],                  // c in registers
    _Float16* __restrict__ hOut,        // h out [px][64], sc1 stores
    _Float16* sbuf,                     // LDS [2 buf][2 chunk][612][8]
    const int (&spb)[3], const int (&slo)[3], int ch16,
    int y0, int x0, int s)
{
    const int tid  = threadIdx.x;
    const int lane = tid & 63;
    const int w    = tid >> 6;
    const int cl   = lane & 31;
    const int l5   = lane >> 5;

    half8 vv[3];

    auto stage_load = [&](int kc) {
        #pragma unroll
        for (int e0 = 0; e0 < 3; ++e0) {
            half8 v = {0, 0, 0, 0, 0, 0, 0, 0};
            const int pb = spb[e0];
            if (pb >= 0) {
                if (CELL == 0) {
                    if (kc == 0) { if (ch16 == 0) v = *(const half8*)(xt + (pb >> 3)); }
                    else v = *(const half8*)(hA + pb + (kc - 1) * 16);
                } else {
                    v = (kc < 4) ? *(const half8*)(hA + pb + kc * 16)
                                 : *(const half8*)(hB + pb + (kc - 4) * 16);
                }
            }
            vv[e0] = v;
        }
    };
    auto stage_write = [&](int b) {
        #pragma unroll
        for (int e0 = 0; e0 < 3; ++e0) {
            if (slo[e0] >= 0)
                *(half8*)(sbuf + b * 9792 + slo[e0]) = vv[e0];
        }
    };

    floatx16 acc[2];
    #pragma unroll
    for (int p_ = 0; p_ < 2; ++p_)
        #pragma unroll
        for (int i = 0; i < 16; ++i) acc[p_][i] = 0.0f;

    __syncthreads();                       // sbuf reuse safety (prev phase reads)
    stage_load(0);
    stage_write(0);
    __syncthreads();

    const int r0 = 2 * w;
    #pragma unroll 1
    for (int kc = 0; kc < NKC; ++kc) {
        if (kc + 1 < NKC) stage_load(kc + 1);
        const _Float16* wk = wlds + (size_t)(kc * 9) * 512 + lane * 8;
        const _Float16* bbase = sbuf + ((size_t)((kc & 1) * 2 + l5) * 612) * 8;

        half8 bufA[3], bufB[3];
        #pragma unroll
        for (int d = 0; d < 3; ++d) {
            bufA[d] = *(const half8*)(bbase + ((r0    ) * 34 + cl + d) * 8);
            bufB[d] = *(const half8*)(bbase + ((r0 + 1) * 34 + cl + d) * 8);
        }
        #pragma unroll
        for (int dx = 0; dx < 3; ++dx) {       // dy = 0: rows r0 / r0+1
            half8 a = *(const half8*)(wk + dx * 512);
            acc[0] = __builtin_amdgcn_mfma_f32_32x32x16_f16(a, bufA[dx], acc[0], 0, 0, 0);
            acc[1] = __builtin_amdgcn_mfma_f32_32x32x16_f16(a, bufB[dx], acc[1], 0, 0, 0);
        }
        #pragma unroll
        for (int d = 0; d < 3; ++d)
            bufA[d] = *(const half8*)(bbase + ((r0 + 2) * 34 + cl + d) * 8);
        #pragma unroll
        for (int dx = 0; dx < 3; ++dx) {       // dy = 1: rows r0+1 / r0+2
            half8 a = *(const half8*)(wk + (3 + dx) * 512);
            acc[0] = __builtin_amdgcn_mfma_f32_32x32x16_f16(a, bufB[dx], acc[0], 0, 0, 0);
            acc[1] = __builtin_amdgcn_mfma_f32_32x32x16_f16(a, bufA[dx], acc[1], 0, 0, 0);
        }
        #pragma unroll
        for (int d = 0; d < 3; ++d)
            bufB[d] = *(const half8*)(bbase + ((r0 + 3) * 34 + cl + d) * 8);
        #pragma unroll
        for (int dx = 0; dx < 3; ++dx) {       // dy = 2: rows r0+2 / r0+3
            half8 a = *(const half8*)(wk + (6 + dx) * 512);
            acc[0] = __builtin_amdgcn_mfma_f32_32x32x16_f16(a, bufA[dx], acc[0], 0, 0, 0);
            acc[1] = __builtin_amdgcn_mfma_f32_32x32x16_f16(a, bufB[dx], acc[1], 0, 0, 0);
        }

        if (kc + 1 < NKC) stage_write((kc + 1) & 1);
        __syncthreads();
    }

    // Epilogue. C/D: col=lane&31 -> px col; reg r=g*4+j -> gate g, hid s*8+4*l5+j.
    #pragma unroll
    for (int pos = 0; pos < 2; ++pos) {
        const int p  = 2 * w + pos;
        const int px = (y0 + p) * HW + x0 + cl;
        half4 hn;
        #pragma unroll
        for (int j = 0; j < 4; ++j) {
            const int bo = CELL * 32 + 4 * l5 + j;
            float iv = sigf(acc[pos][     j] + blds[bo]);
            float fv = sigf(acc[pos][ 4 + j] + blds[bo + 8]);
            float ov = sigf(acc[pos][ 8 + j] + blds[bo + 16]);
            float gv = tanhf_(acc[pos][12 + j] + blds[bo + 24]);
            float cv = fv * cr[pos][j] + iv * gv;
            cr[pos][j] = cv;
            hn[j] = (_Float16)(ov * tanhf_(cv));
        }
        st_coh8(hOut + (size_t)px * 64 + s * 8 + 4 * l5, hn);
    }
}

// Readout 64->1 conv. Block s handles patch s (8x8) of its group tile.
__device__ __forceinline__ void readout_phase(
    const _Float16* __restrict__ h1, const float* wl, float brv,
    float* __restrict__ yout, _Float16* sbuf,
    const int (&rpb)[2], const int (&rlo)[2], int ch8, int yidx)
{
    const int tid = threadIdx.x;

    half8 rv[2];
    #pragma unroll
    for (int e0 = 0; e0 < 2; ++e0) {
        half8 v = {0, 0, 0, 0, 0, 0, 0, 0};
        if (rpb[e0] >= 0) v = *(const half8*)(h1 + rpb[e0]);
        rv[e0] = v;
    }
    __syncthreads();                       // prior sbuf reads complete
    #pragma unroll
    for (int e0 = 0; e0 < 2; ++e0)
        if (rlo[e0] >= 0) *(half8*)(sbuf + rlo[e0]) = rv[e0];
    __syncthreads();

    const int sub = tid & 7;
    const int p   = tid >> 3;
    const int pr  = p >> 3, pcc = p & 7;
    float sacc = 0.0f;
    #pragma unroll
    for (int dy = 0; dy < 3; ++dy)
        #pragma unroll
        for (int dx = 0; dx < 3; ++dx) {
            int pc = (pr + dy) * 10 + (pcc + dx);
            half8 hv = *(const half8*)(sbuf + ((size_t)pc * 8 + sub) * 8);
            int tap = dy * 3 + dx;
            #pragma unroll
            for (int j = 0; j < 8; ++j)
                sacc += wl[(sub * 8 + j) * 9 + tap] * (float)hv[j];
        }
    sacc += __shfl_xor(sacc, 1);
    sacc += __shfl_xor(sacc, 2);
    sacc += __shfl_xor(sacc, 4);
    if (sub == 0) st_coh4(yout + yidx, sacc + brv);
}

// LDS map (dynamic, 161536 B): wlds @0 (119808), sbuf @119808 (39168),
// wl @158976 (2304), blds @161280 (256).
// Schedule per t: cell1(t); GRID_SYNC; fence; cell2(t); readout(t-1).
__global__ __launch_bounds__(512, 2)
void mega(const _Float16* __restrict__ xh, const _Float16* __restrict__ WpG,
          const float* __restrict__ b0g, const float* __restrict__ b1g,
          const float* __restrict__ Wr, const float* __restrict__ br,
          _Float16* __restrict__ h0a, _Float16* __restrict__ h0b,
          _Float16* __restrict__ h1a, _Float16* __restrict__ h1b,
          float* __restrict__ y, unsigned* slots, unsigned* rel)
{
    extern __shared__ __align__(16) char dyn[];
    _Float16* wlds = (_Float16*)dyn;
    _Float16* sbuf = (_Float16*)(dyn + 119808);
    float*    wl   = (float*)(dyn + 158976);
    float*    blds = (float*)(dyn + 161280);

    const int tid = threadIdx.x;
    const int bid = blockIdx.x;
    const int s = bid >> 5, g = bid & 31;
    const int y0 = (g >> 2) * 16, x0 = (g & 3) * 32;

    // one-time: weight slice + readout weights + biases into LDS
    const half8* wsrc = (const half8*)(WpG + (size_t)s * 59904);
    for (int i = tid; i < 7488; i += 512) ((half8*)wlds)[i] = wsrc[i];
    for (int i = tid; i < 576; i += 512) wl[i] = Wr[i];
    if (tid < 64) {
        int cell = tid >> 5, gj = tid & 31;
        int gate = gj >> 3, h8 = gj & 7;
        blds[tid] = (cell ? b1g : b0g)[gate * 64 + s * 8 + h8];
    }
    const float brv = br[0];
    float c0r[2][4] = {{0, 0, 0, 0}, {0, 0, 0, 0}};
    float c1r[2][4] = {{0, 0, 0, 0}, {0, 0, 0, 0}};

    // ---- t-invariant staging index precompute ----
    const int ch16 = tid & 1;
    int spb[3], slo[3];
    #pragma unroll
    for (int e0 = 0; e0 < 3; ++e0) {
        int e = tid + e0 * 512;
        spb[e0] = -1; slo[e0] = -1;
        if (e < 1224) {
            int pc = e >> 1;
            int r = pc / 34, c = pc - r * 34;
            int gy = y0 - 1 + r, gx = x0 - 1 + c;
            slo[e0] = (ch16 * 612 + pc) * 8;
            if (gy >= 0 && gy < HW && gx >= 0 && gx < HW)
                spb[e0] = (gy * HW + gx) * 64 + ch16 * 8;
        }
    }
    const int ch8 = tid & 7;
    const int py0 = y0 + (s >> 2) * 8, px0 = x0 + (s & 3) * 8;
    int rpb[2], rlo[2];
    #pragma unroll
    for (int e0 = 0; e0 < 2; ++e0) {
        int e = tid + e0 * 512;
        rpb[e0] = -1; rlo[e0] = -1;
        if (e < 800) {
            int pc = e >> 3;
            int r = pc / 10, c = pc - r * 10;
            int gy = py0 - 1 + r, gx = px0 - 1 + c;
            rlo[e0] = (pc * 8 + ch8) * 8;
            if (gy >= 0 && gy < HW && gx >= 0 && gx < HW)
                rpb[e0] = (gy * HW + gx) * 64 + ch8 * 8;
        }
    }
    const int yidx = (py0 + ((tid >> 3) >> 3)) * HW + px0 + ((tid >> 3) & 7);

    __syncthreads();
    __builtin_amdgcn_fence(__ATOMIC_ACQUIRE, "agent");

    #pragma unroll 1
    for (int t = 0; t < 32; ++t) {
        const _Float16* xt = xh + (size_t)t * NPIX * 8;
        _Float16* h0r = (t & 1) ? h0b : h0a;
        _Float16* h0w = (t & 1) ? h0a : h0b;
        _Float16* h1r = (t & 1) ? h1b : h1a;
        _Float16* h1w = (t & 1) ? h1a : h1b;

        cell_phase<5, 0>(xt, h0r, nullptr, wlds, blds, c0r, h0w, sbuf,
                         spb, slo, ch16, y0, x0, s);
        grid_sync(slots, rel, bid, (unsigned)(t + 1));
        __builtin_amdgcn_fence(__ATOMIC_ACQUIRE, "agent");   // inv L1+L2 -> fresh h

        cell_phase<8, 1>(nullptr, h0w, h1r, wlds + 23040, blds, c1r, h1w, sbuf,
                         spb, slo, ch16, y0, x0, s);
        if (t > 0) readout_phase(h1r, wl, brv, y + (size_t)(t - 1) * NPIX, sbuf,
                                 rpb, rlo, ch8, yidx);
    }
    grid_sync(slots, rel, bid, 33u);
    __builtin_amdgcn_fence(__ATOMIC_ACQUIRE, "agent");
    readout_phase(h1a, wl, brv, y + (size_t)31 * NPIX, sbuf, rpb, rlo, ch8, yidx);
}

// ---------------------------------------------------------------------------
// Weight repack: W [256][CIN_W][3][3] fp32 -> WpG [8 s][cell][kc][tap][512] fp16.
// A row rr (=lane&31): gate = rr>>3, hid = s*8 + (rr&7); k = kc*16 + (l>>5)*8 + j.
// ---------------------------------------------------------------------------
__global__ void pack_w(const float* __restrict__ W, _Float16* __restrict__ Wp,
                       int NKC, int CIN_W, int cell1, int base, int total)
{
    int idx = blockIdx.x * 256 + threadIdx.x;
    if (idx >= total) return;
    int j = idx & 7, l = (idx >> 3) & 63;
    int rest = idx >> 9;
    int tap = rest % 9;
    int kt  = rest / 9;
    int kc = kt % NKC, s = kt / NKC;
    int rr = l & 31, l5 = l >> 5;
    int o = (rr >> 3) * 64 + s * 8 + (rr & 7);
    int k = kc * 16 + l5 * 8 + j;
    int cin = cell1 ? ((k < 4) ? k : ((k >= 16 && k < 80) ? k - 12 : -1)) : k;
    float v = (cin >= 0) ? W[((size_t)o * CIN_W + cin) * 9 + tap] : 0.0f;
    Wp[(size_t)s * 59904 + base + (size_t)(kc * 9 + tap) * 512 + l * 8 + j] = (_Float16)v;
}

// x [32][4][128][128] fp32 -> xh [32][px][8] fp16 (ch 0-3 real, 4-7 zero)
__global__ void xconv(const float* __restrict__ x, _Float16* __restrict__ xh)
{
    int idx = blockIdx.x * 256 + threadIdx.x;       // 524288
    int t = idx >> 14, px = idx & 16383;
    const float* xs = x + (size_t)t * 4 * NPIX + px;
    half8 v = {0, 0, 0, 0, 0, 0, 0, 0};
    v[0] = (_Float16)xs[0];
    v[1] = (_Float16)xs[NPIX];
    v[2] = (_Float16)xs[2 * NPIX];
    v[3] = (_Float16)xs[3 * NPIX];
    *(half8*)(xh + (size_t)idx * 8) = v;
}

extern "C" void kernel_launch(void* const* d_in, const int* in_sizes, int n_in,
                              void* d_out, int out_size, void* d_ws, size_t ws_size,
                              hipStream_t stream)
{
    const float* x  = (const float*)d_in[0];
    const float* W0 = (const float*)d_in[1];
    const float* b0 = (const float*)d_in[2];
    const float* W1 = (const float*)d_in[3];
    const float* b1 = (const float*)d_in[4];
    const float* Wr = (const float*)d_in[5];
    const float* br = (const float*)d_in[6];
    float* y = (float*)d_out;

    char* ws = (char*)d_ws;
    _Float16* h0a = (_Float16*)(ws);                    // 2 MB (zeroed)
    _Float16* h1a = (_Float16*)(ws + (2u << 20));       // 2 MB (zeroed)
    _Float16* h0b = (_Float16*)(ws + (4u << 20));       // 2 MB
    _Float16* h1b = (_Float16*)(ws + (6u << 20));       // 2 MB
    _Float16* xh  = (_Float16*)(ws + (8u << 20));       // 8 MB
    _Float16* WpG = (_Float16*)(ws + (16u << 20));      // 936 KB
    unsigned* cnt = (unsigned*)(ws + (17u << 20));      // slots 16 KB + rel

    // zero t=0 recurrent state (h0a, h1a) + barrier slots/release
    hipMemsetAsync(ws, 0, (4u << 20), stream);
    hipMemsetAsync(cnt, 0, 256 * 64 + 64, stream);

    pack_w<<<dim3((184320 + 255) / 256), 256, 0, stream>>>(W0, WpG, 5, 68, 1, 0, 184320);
    pack_w<<<dim3((294912 + 255) / 256), 256, 0, stream>>>(W1, WpG, 8, 128, 0, 23040, 294912);
    xconv<<<dim3(2048), 256, 0, stream>>>(x, xh);

    hipFuncSetAttribute(reinterpret_cast<const void*>(mega),
                        hipFuncAttributeMaxDynamicSharedMemorySize, 161536);
    mega<<<dim3(256), 512, 161536, stream>>>(xh, WpG, b0, b1, Wr, br,
                                             h0a, h0b, h1a, h1b, y,
                                             cnt, cnt + 256 * 16);
}